// Round 7
// baseline (2109.939 us; speedup 1.0000x reference)
//
#include <hip/hip_runtime.h>

typedef unsigned int uint;
#define DI __device__ __forceinline__

typedef __bf16 bf16;
typedef __attribute__((ext_vector_type(4))) float f32x4;
typedef __attribute__((ext_vector_type(8))) __bf16 bf16x8;
typedef __attribute__((ext_vector_type(4))) int i32x4;

// ---------------- ws layout (float units) ----------------
constexpr size_t OFF_A    = 0;                    // y1/y2 bf16 [N][C][T]
constexpr size_t OFF_B    = 33554432;             // pool1t bf16
constexpr size_t OFF_B1   = OFF_B + 16777216;     // pool2t bf16 [2048][128][128]
constexpr size_t OFF_WHHG = 67108864;             // bf16 [2][512][128]
constexpr size_t OFF_WIHG = OFF_WHHG + 65536;     // bf16 [2][512][128]
constexpr size_t OFF_BIAS = OFF_WIHG + 65536;     // f32 [2][512]
constexpr size_t OFF_HSUM = OFF_BIAS + 1024;      // f32 [2][2048][128]
constexpr size_t OFF_FEAT = OFF_HSUM + 524288;    // f32 [2048][256]
constexpr size_t OFF_WH1  = OFF_FEAT + 524288;    // f32 [2048][128]
constexpr size_t OFF_S1A  = OFF_WH1 + 262144;
constexpr size_t OFF_S2A  = OFF_S1A + 2048;
constexpr size_t OFF_H1   = OFF_S2A + 2048;
constexpr size_t OFF_WH2  = OFF_H1 + 262144;
constexpr size_t OFF_S1B  = OFF_WH2 + 262144;
constexpr size_t OFF_S2B  = OFF_S1B + 2048;
constexpr size_t OFF_STAT = OFF_S2B + 2048;       // sum/sumsq/scale/shift
constexpr size_t OFF_W1P  = OFF_STAT + 512;       // bf16 12288 (pre-swizzled conv1 w)
constexpr size_t OFF_W2P  = OFF_W1P + 6144;       // bf16 24576 (pre-swizzled conv2 w)
constexpr size_t OFF_WHT  = OFF_W2P + 12288;      // bf16 [128][2048] (WhT, reused both layers)

DI float bflo(uint u){ union { uint i; float f; } v; v.i = u << 16;         return v.f; }
DI float bfhi(uint u){ union { uint i; float f; } v; v.i = u & 0xffff0000u; return v.f; }
DI float fexp2_(float x){ return __builtin_amdgcn_exp2f(x); }
DI float frcp_(float x){ return __builtin_amdgcn_rcpf(x); }
DI float sigf_(float x){ return frcp_(1.0f + fexp2_(x * -1.44269504f)); }
// tanh(x) = 1 - 2/(e^{2x}+1); saturates correctly at +/-inf
DI float tanhx_(float x){ return 1.0f - 2.0f*frcp_(1.0f + fexp2_(x * 2.88539009f)); }

DI f32x4 mfma16(i32x4 a, i32x4 b, f32x4 c){
  return __builtin_amdgcn_mfma_f32_16x16x32_bf16(
      __builtin_bit_cast(bf16x8, a), __builtin_bit_cast(bf16x8, b), c, 0, 0, 0);
}

// swizzled LDS address helpers (XOR bits[4:6] by row&7)
DI char* swz128(char* base, int row, int byteInRow){ return base + row*128 + (byteInRow ^ ((row&7)<<4)); }
DI char* swz256(char* base, int row, int byteInRow){ return base + row*256 + (byteInRow ^ ((row&7)<<4)); }

// ---------------- prep: gate-interleaved LSTM weights + pre-swizzled conv weights ----------------
__global__ void prep_kernel(const float* __restrict__ whf, const float* __restrict__ whr,
                            const float* __restrict__ wif, const float* __restrict__ wir,
                            const float* __restrict__ bfv, const float* __restrict__ brv,
                            const float* __restrict__ c1w, const float* __restrict__ c2w,
                            bf16* __restrict__ whh_g, bf16* __restrict__ wih_g,
                            float* __restrict__ bias_g,
                            bf16* __restrict__ w1p, bf16* __restrict__ w2p)
{
  const int dir = blockIdx.y;
  const float* whh = dir ? whr : whf;
  const float* wih = dir ? wir : wif;
  const float* bb  = dir ? brv : bfv;
  int idx = blockIdx.x*256 + threadIdx.x;        // < 65536
  int c = idx >> 7, d = idx & 127;
  int src = ((c & 3)*128 + (c >> 2))*128 + d;
  whh_g[(size_t)dir*65536 + idx] = (bf16)whh[src];
  wih_g[(size_t)dir*65536 + idx] = (bf16)wih[src];
  if (idx < 512) bias_g[dir*512 + idx] = bb[(idx & 3)*128 + (idx >> 2)];
  if (dir == 0) {
    if (idx < 12288) {
      int row = idx >> 6;
      int ci = (((idx & 63)*2) ^ ((row & 7) << 4)) >> 1;
      int co = row & 63, dk = row >> 6;
      w1p[idx] = (bf16)c1w[(co*64 + ci)*3 + dk];
    }
    if (idx < 24576) {
      int row = idx >> 6;
      int ci = (((idx & 63)*2) ^ ((row & 7) << 4)) >> 1;
      int co = row & 127, dk = row >> 7;
      w2p[idx] = (bf16)c2w[(co*64 + ci)*3 + dk];
    }
  }
}

// ---------------- conv1: x f32 [2048][64][512] -> y1 bf16 [2048][64][512] ----------------
__global__ __launch_bounds__(512) void conv1_kernel(
    const float* __restrict__ x, const bf16* __restrict__ w1p,
    const float* __restrict__ bias, bf16* __restrict__ y)
{
  __shared__ bf16 xa[258*64];     // [row=t-t0+1][ci], 128B rows, swizzled
  __shared__ bf16 wb[3*64*64];    // [dk*64+co][ci], swizzled (pre-swizzled copy)
  const int n = blockIdx.y, t0 = blockIdx.x*256, tid = threadIdx.x;
  {
    const i32x4* wsrc = (const i32x4*)w1p;
    for (int i = tid; i < 1536; i += 512) ((i32x4*)wb)[i] = wsrc[i];
  }
  for (int i = tid; i < 4096; i += 512) {
    int q = i & 63, ci = i >> 6;
    float4 v = *(const float4*)&x[((size_t)n*64 + ci)*512 + t0 + q*4];
    int row = q*4 + 1;
    *(bf16*)swz128((char*)xa, row+0, ci*2) = (bf16)v.x;
    *(bf16*)swz128((char*)xa, row+1, ci*2) = (bf16)v.y;
    *(bf16*)swz128((char*)xa, row+2, ci*2) = (bf16)v.z;
    *(bf16*)swz128((char*)xa, row+3, ci*2) = (bf16)v.w;
  }
  if (tid < 128) {
    int ci = tid >> 1, e = tid & 1;
    int row = e ? 257 : 0;
    int t = t0 + (e ? 256 : -1);
    float v = (t >= 0 && t < 512) ? x[((size_t)n*64 + ci)*512 + t] : 0.0f;
    *(bf16*)swz128((char*)xa, row, ci*2) = (bf16)v;
  }
  __syncthreads();
  const int lane = tid & 63, wv = tid >> 6;
  const int m0 = (wv & 3)*64, c0 = (wv >> 2)*32;
  const int l15 = lane & 15, lh = lane >> 4;
  f32x4 acc[4][2];
  #pragma unroll
  for (int mf = 0; mf < 4; ++mf)
    #pragma unroll
    for (int cf = 0; cf < 2; ++cf) {
      float bb = bias[c0 + cf*16 + l15];
      acc[mf][cf] = (f32x4){bb, bb, bb, bb};
    }
  #pragma unroll
  for (int dk = 0; dk < 3; ++dk)
    #pragma unroll
    for (int ks = 0; ks < 2; ++ks) {
      const int kb = ks*64 + lh*16;
      i32x4 bfr[2], afr[4];
      #pragma unroll
      for (int cf = 0; cf < 2; ++cf) {
        int row = dk*64 + c0 + cf*16 + l15;
        bfr[cf] = *(const i32x4*)swz128((char*)wb, row, kb);
      }
      #pragma unroll
      for (int mf = 0; mf < 4; ++mf) {
        int row = m0 + mf*16 + l15 + dk;
        afr[mf] = *(const i32x4*)swz128((char*)xa, row, kb);
      }
      #pragma unroll
      for (int mf = 0; mf < 4; ++mf)
        #pragma unroll
        for (int cf = 0; cf < 2; ++cf)
          acc[mf][cf] = mfma16(afr[mf], bfr[cf], acc[mf][cf]);
    }
  #pragma unroll
  for (int mf = 0; mf < 4; ++mf)
    #pragma unroll
    for (int cf = 0; cf < 2; ++cf) {
      int co = c0 + cf*16 + l15;
      int tt = t0 + m0 + mf*16 + lh*4;
      union { bf16 h[4]; uint2 u; } pk;
      #pragma unroll
      for (int r = 0; r < 4; ++r) pk.h[r] = (bf16)acc[mf][cf][r];
      *(uint2*)&y[((size_t)n*64 + co)*512 + tt] = pk.u;
    }
}

// ---------------- conv2: pool1T bf16 [2048][256][64] -> y2 bf16 [2048][128][256] ----------------
__global__ __launch_bounds__(512) void conv2_kernel(
    const bf16* __restrict__ xin, const bf16* __restrict__ w2p,
    const float* __restrict__ bias, bf16* __restrict__ y)
{
  __shared__ bf16 xa[258*64];
  __shared__ bf16 wb[3*128*64];
  const int n = blockIdx.x, tid = threadIdx.x;
  {
    const i32x4* wsrc = (const i32x4*)w2p;
    for (int i = tid; i < 3072; i += 512) ((i32x4*)wb)[i] = wsrc[i];
  }
  {
    const i32x4* src = (const i32x4*)(xin + (size_t)n*256*64);
    for (int i = tid; i < 2048; i += 512) {
      int row = (i >> 3) + 1, blk = i & 7;
      *(i32x4*)swz128((char*)xa, row, blk*16) = src[i];
    }
  }
  if (tid < 128) {
    int ci = tid >> 1, e = tid & 1;
    int row = e ? 257 : 0;
    *(bf16*)swz128((char*)xa, row, ci*2) = (bf16)0.0f;
  }
  __syncthreads();
  const int lane = tid & 63, wv = tid >> 6;
  const int m0 = (wv & 3)*64, c0 = (wv >> 2)*64;
  const int l15 = lane & 15, lh = lane >> 4;
  f32x4 acc[4][4];
  #pragma unroll
  for (int mf = 0; mf < 4; ++mf)
    #pragma unroll
    for (int cf = 0; cf < 4; ++cf) {
      float bb = bias[c0 + cf*16 + l15];
      acc[mf][cf] = (f32x4){bb, bb, bb, bb};
    }
  #pragma unroll
  for (int dk = 0; dk < 3; ++dk)
    #pragma unroll
    for (int ks = 0; ks < 2; ++ks) {
      const int kb = ks*64 + lh*16;
      i32x4 bfr[4], afr[4];
      #pragma unroll
      for (int cf = 0; cf < 4; ++cf) {
        int row = dk*128 + c0 + cf*16 + l15;
        bfr[cf] = *(const i32x4*)swz128((char*)wb, row, kb);
      }
      #pragma unroll
      for (int mf = 0; mf < 4; ++mf) {
        int row = m0 + mf*16 + l15 + dk;
        afr[mf] = *(const i32x4*)swz128((char*)xa, row, kb);
      }
      #pragma unroll
      for (int mf = 0; mf < 4; ++mf)
        #pragma unroll
        for (int cf = 0; cf < 4; ++cf)
          acc[mf][cf] = mfma16(afr[mf], bfr[cf], acc[mf][cf]);
    }
  #pragma unroll
  for (int mf = 0; mf < 4; ++mf)
    #pragma unroll
    for (int cf = 0; cf < 4; ++cf) {
      int co = c0 + cf*16 + l15;
      int tt = m0 + mf*16 + lh*4;
      union { bf16 h[4]; uint2 u; } pk;
      #pragma unroll
      for (int r = 0; r < 4; ++r) pk.h[r] = (bf16)acc[mf][cf][r];
      *(uint2*)&y[((size_t)n*128 + co)*256 + tt] = pk.u;
    }
}

// ---------------- BN stats (vectorized uint4 loads) ----------------
__global__ __launch_bounds__(256) void bn_stats_kernel(
    const bf16* __restrict__ y, float* __restrict__ stat, int C, int T)
{
  const int c = blockIdx.x, n0 = blockIdx.y*64, tid = threadIdx.x;
  float s = 0.f, q = 0.f;
  const int qpr = T >> 3;           // uint4 (8 bf16) per row
  for (int i = tid; i < 64*qpr; i += 256) {
    int n = n0 + i/qpr, qd = i & (qpr - 1);
    uint4 u = *(const uint4*)&y[((size_t)n*C + c)*T + qd*8];
    float v0 = bflo(u.x), v1 = bfhi(u.x), v2 = bflo(u.y), v3 = bfhi(u.y);
    float v4 = bflo(u.z), v5 = bfhi(u.z), v6 = bflo(u.w), v7 = bfhi(u.w);
    s += (v0+v1)+(v2+v3)+((v4+v5)+(v6+v7));
    q += (v0*v0+v1*v1)+(v2*v2+v3*v3)+((v4*v4+v5*v5)+(v6*v6+v7*v7));
  }
  __shared__ float rs[256], rq[256];
  rs[tid] = s; rq[tid] = q; __syncthreads();
  for (int off = 128; off > 0; off >>= 1) {
    if (tid < off) { rs[tid] += rs[tid+off]; rq[tid] += rq[tid+off]; }
    __syncthreads();
  }
  if (tid == 0) { atomicAdd(&stat[c], rs[0]); atomicAdd(&stat[128+c], rq[0]); }
}

__global__ void bn_finalize_kernel(float* __restrict__ stat, const float* __restrict__ g,
                                   const float* __restrict__ b, int C, float invCnt)
{
  int c = threadIdx.x;
  if (c < C) {
    float m  = stat[c]*invCnt;
    float v  = stat[128+c]*invCnt - m*m;
    float sc = g[c]*rsqrtf(v + 1e-5f);
    stat[256+c] = sc;
    stat[384+c] = b[c] - m*sc;
  }
}

// ---------------- BN apply + ReLU + maxpool2 + transpose ----------------
template<int C, int TH>
__global__ __launch_bounds__(256) void poolT_kernel(
    const bf16* __restrict__ yin, const float* __restrict__ stat, bf16* __restrict__ outp)
{
  __shared__ bf16 buf[C][TH + 2];
  const int n = blockIdx.x, tid = threadIdx.x;
  const uint* src = (const uint*)(yin + (size_t)n*C*TH*2);
  for (int i = tid; i < C*TH; i += 256) {
    int th = i & (TH - 1), c = i / TH;
    uint u = src[i];
    float sc = stat[256 + c], sh = stat[384 + c];
    float a = fmaxf(sc*bflo(u) + sh, 0.f);
    float b = fmaxf(sc*bfhi(u) + sh, 0.f);
    buf[c][th] = (bf16)fmaxf(a, b);
  }
  __syncthreads();
  bf16* dst = outp + (size_t)n*TH*C;
  for (int i = tid; i < TH*C/2; i += 256) {
    int cp = i & (C/2 - 1), th = i / (C/2);
    union { bf16 h[2]; uint u; } pk;
    pk.h[0] = buf[2*cp][th]; pk.h[1] = buf[2*cp + 1][th];
    *(uint*)&dst[th*C + 2*cp] = pk.u;
  }
}

// ---------------- fused biLSTM: 8 nodes/block, 2 blocks/CU (independent barriers) ----------------
// grid 512 = (256 node-groups x 2 dirs), block 512 = 8 waves; wave wv owns gate-cols
// [wv*64, wv*64+64). mfma16(weight, x/h): col=node=l15 (only 0-7 valid), row = gates
// i,f,g,o of (node=l15, hh=wv*16+cf*4+lh). Lanes l15>=8 compute discarded duplicates.
// h double-buffered in 8KB LDS; 1 barrier/t; setprio around MFMA clusters.
__global__ __launch_bounds__(512, 4) void lstm_fused_kernel(
    const bf16* __restrict__ p2t, const bf16* __restrict__ wih_g,
    const bf16* __restrict__ whh_g, const float* __restrict__ bias_g,
    float* __restrict__ hsum)
{
  __shared__ bf16 hb[2][2048];   // [buf][16 rows][128 hh]; rows 8-15 stay zero
  const int z = blockIdx.x;
  const int dir = z & 1, n0 = (z >> 1)*8;
  const int tid = threadIdx.x, lane = tid & 63, wv = tid >> 6;
  const int l15 = lane & 15, lh = lane >> 4;
  i32x4 wihr[4][4], whhr[4][4];
  {
    const bf16* wi = wih_g + (size_t)dir*65536;
    const bf16* wh = whh_g + (size_t)dir*65536;
    #pragma unroll
    for (int cf = 0; cf < 4; ++cf) {
      int c = wv*64 + cf*16 + l15;
      #pragma unroll
      for (int ks = 0; ks < 4; ++ks) {
        wihr[cf][ks] = *(const i32x4*)(wi + (size_t)c*128 + ks*32 + lh*8);
        whhr[cf][ks] = *(const i32x4*)(wh + (size_t)c*128 + ks*32 + lh*8);
      }
    }
  }
  f32x4 bias4[4];
  #pragma unroll
  for (int cf = 0; cf < 4; ++cf) {
    int hh = wv*16 + cf*4 + lh;
    bias4[cf] = *(const f32x4*)&bias_g[dir*512 + hh*4];
  }
  for (int i = tid; i < 512; i += 512) ((i32x4*)hb)[i] = (i32x4){0,0,0,0};  // both buffers
  const bf16* xrow = p2t + (size_t)(n0 + (l15 & 7))*128*128;
  float creg[4] = {0.f,0.f,0.f,0.f}, hac[4] = {0.f,0.f,0.f,0.f};
  f32x4 acc[4];
  i32x4 xn[4];
  { // prologue: acc = bias + x(t=0) @ wih
    int ts0 = dir ? 127 : 0;
    #pragma unroll
    for (int ks = 0; ks < 4; ++ks)
      xn[ks] = *(const i32x4*)(xrow + (size_t)ts0*128 + ks*32 + lh*8);
    #pragma unroll
    for (int cf = 0; cf < 4; ++cf) {
      acc[cf] = mfma16(wihr[cf][0], xn[0], bias4[cf]);
      #pragma unroll
      for (int ks = 1; ks < 4; ++ks)
        acc[cf] = mfma16(wihr[cf][ks], xn[ks], acc[cf]);
    }
  }
  int cur = 0;
  __syncthreads();
  for (int t = 0; t < 128; ++t) {
    { // load x(t+1) early (consumed after nonlin)
      int tn = (t + 1 < 128) ? t + 1 : 127;
      int tsn = dir ? 127 - tn : tn;
      #pragma unroll
      for (int ks = 0; ks < 4; ++ks)
        xn[ks] = *(const i32x4*)(xrow + (size_t)tsn*128 + ks*32 + lh*8);
    }
    // recurrence: acc += h(t-1) @ whh
    __builtin_amdgcn_s_setprio(1);
    {
      i32x4 a0 = *(const i32x4*)swz256((char*)hb[cur], l15, 0*64 + lh*16);
      i32x4 a1 = *(const i32x4*)swz256((char*)hb[cur], l15, 1*64 + lh*16);
      #pragma unroll
      for (int cf = 0; cf < 4; ++cf) {
        acc[cf] = mfma16(whhr[cf][0], a0, acc[cf]);
        acc[cf] = mfma16(whhr[cf][1], a1, acc[cf]);
      }
      a0 = *(const i32x4*)swz256((char*)hb[cur], l15, 2*64 + lh*16);
      a1 = *(const i32x4*)swz256((char*)hb[cur], l15, 3*64 + lh*16);
      #pragma unroll
      for (int cf = 0; cf < 4; ++cf) {
        acc[cf] = mfma16(whhr[cf][2], a0, acc[cf]);
        acc[cf] = mfma16(whhr[cf][3], a1, acc[cf]);
      }
    }
    __builtin_amdgcn_s_setprio(0);
    // nonlinearity: regs = gates i,f,g,o directly
    #pragma unroll
    for (int cf = 0; cf < 4; ++cf) {
      float ig = sigf_(acc[cf][0]);
      float fg = sigf_(acc[cf][1]);
      float gg = tanhx_(acc[cf][2]);
      float og = sigf_(acc[cf][3]);
      float cv = fg*creg[cf] + ig*gg;
      creg[cf] = cv;
      float hv = og*tanhx_(cv);
      hac[cf] += hv;
      if (l15 < 8) {
        int hh = wv*16 + cf*4 + lh;
        *(bf16*)swz256((char*)hb[cur^1], l15, hh*2) = (bf16)hv;
      }
    }
    // inproj for t+1 (independent of h; overlaps other waves' VALU / barrier)
    __builtin_amdgcn_s_setprio(1);
    #pragma unroll
    for (int cf = 0; cf < 4; ++cf) {
      acc[cf] = mfma16(wihr[cf][0], xn[0], bias4[cf]);
      #pragma unroll
      for (int ks = 1; ks < 4; ++ks)
        acc[cf] = mfma16(wihr[cf][ks], xn[ks], acc[cf]);
    }
    __builtin_amdgcn_s_setprio(0);
    __syncthreads();
    cur ^= 1;
  }
  if (l15 < 8) {
    float* hm = hsum + ((size_t)dir*2048 + n0)*128;
    #pragma unroll
    for (int cf = 0; cf < 4; ++cf) {
      int hh = wv*16 + cf*4 + lh;
      hm[(size_t)l15*128 + hh] = hac[cf];
    }
  }
}

// ---------------- feats = mean over T of [hf, hr] ----------------
__global__ __launch_bounds__(256) void feats_kernel(const float* __restrict__ hsum, float* __restrict__ feats)
{
  int idx = blockIdx.x*256 + threadIdx.x;
  int k = idx & 255, n = idx >> 8;
  float v = (k < 128) ? hsum[(size_t)n*128 + k]
                      : hsum[(size_t)2048*128 + (size_t)n*128 + (k - 128)];
  feats[idx] = v * 0.0078125f;
}

// ---------------- Wh = in @ W^T  ([2048,K] x [128,K]); also emits WhT bf16 [128][2048] ----------------
template<int K>
__global__ __launch_bounds__(256) void node_gemm_kernel(
    const float* __restrict__ inp, const float* __restrict__ W,
    float* __restrict__ outp, bf16* __restrict__ outT)
{
  __shared__ float ft[32][K];
  const int i0 = blockIdx.x*32, tid = threadIdx.x;
  for (int i = tid; i < 32*K; i += 256) ft[i/K][i%K] = inp[(size_t)i0*K + i];
  __syncthreads();
  const int f = tid & 127, ih = (tid >> 7)*16;
  float acc[16];
  #pragma unroll
  for (int ii = 0; ii < 16; ++ii) acc[ii] = 0.f;
  const float* wp = W + (size_t)f*K;
  for (int k = 0; k < K; k += 4) {
    const float4 wv = *reinterpret_cast<const float4*>(&wp[k]);
    #pragma unroll
    for (int ii = 0; ii < 16; ++ii) {
      const float* fp = &ft[ih+ii][k];
      acc[ii] += fp[0]*wv.x + fp[1]*wv.y + fp[2]*wv.z + fp[3]*wv.w;
    }
  }
  union { bf16 h[16]; uint4 u[2]; } pk;
  #pragma unroll
  for (int ii = 0; ii < 16; ++ii) {
    outp[(size_t)(i0+ih+ii)*128 + f] = acc[ii];
    pk.h[ii] = (bf16)acc[ii];
  }
  uint4* dT = (uint4*)&outT[(size_t)f*2048 + i0 + ih];
  dT[0] = pk.u[0]; dT[1] = pk.u[1];
}

// ---------------- s1/s2 per node ----------------
__global__ __launch_bounds__(256) void gat_s_kernel(const float* __restrict__ Wh,
    const float* __restrict__ a, float* __restrict__ s1, float* __restrict__ s2)
{
  const int node = blockIdx.x*4 + (threadIdx.x >> 6);
  const int l = threadIdx.x & 63;
  const float w0 = Wh[(size_t)node*128 + l], w1 = Wh[(size_t)node*128 + 64 + l];
  float v1 = w0*a[l]     + w1*a[64+l];
  float v2 = w0*a[128+l] + w1*a[192+l];
  #pragma unroll
  for (int off = 32; off > 0; off >>= 1) { v1 += __shfl_down(v1, off); v2 += __shfl_down(v2, off); }
  if (l == 0) { s1[node] = v1; s2[node] = v2; }
}

// ---------------- GAT attention, 16 rows/block, MFMA aggregation ----------------
__global__ __launch_bounds__(512) void gat_attn16_kernel(
    const bf16* __restrict__ WhT,
    const float* __restrict__ s1, const float* __restrict__ s2v,
    const int* __restrict__ adj, float* __restrict__ outp, int applyElu)
{
  __shared__ bf16 P[16*2048];     // rows of 4096B, swizzled
  __shared__ float sums[16];
  const int i0 = blockIdx.x*16, tid = threadIdx.x;
  const int lane = tid & 63, w = tid >> 6;
  for (int rr = 0; rr < 2; ++rr) {
    const int r = w*2 + rr, i = i0 + r;
    const float s1i = s1[i];
    const int4* arow = (const int4*)(adj + (size_t)i*2048);
    float ev[8][4];
    float m = -3.0e38f;
    #pragma unroll
    for (int k = 0; k < 8; ++k) {
      int4 ad = arow[k*64 + lane];
      float4 sv = *(const float4*)&s2v[k*256 + lane*4];
      float e0 = s1i + sv.x; e0 = (e0 > 0.f) ? e0 : 0.2f*e0; e0 = (ad.x > 0) ? e0 : -3.0e38f;
      float e1 = s1i + sv.y; e1 = (e1 > 0.f) ? e1 : 0.2f*e1; e1 = (ad.y > 0) ? e1 : -3.0e38f;
      float e2 = s1i + sv.z; e2 = (e2 > 0.f) ? e2 : 0.2f*e2; e2 = (ad.z > 0) ? e2 : -3.0e38f;
      float e3 = s1i + sv.w; e3 = (e3 > 0.f) ? e3 : 0.2f*e3; e3 = (ad.w > 0) ? e3 : -3.0e38f;
      ev[k][0]=e0; ev[k][1]=e1; ev[k][2]=e2; ev[k][3]=e3;
      m = fmaxf(m, fmaxf(fmaxf(e0,e1), fmaxf(e2,e3)));
    }
    #pragma unroll
    for (int off = 32; off > 0; off >>= 1) m = fmaxf(m, __shfl_xor(m, off));
    float s = 0.f;
    char* prow = (char*)P + r*4096;
    #pragma unroll
    for (int k = 0; k < 8; ++k) {
      float p0 = __expf(ev[k][0] - m);
      float p1 = __expf(ev[k][1] - m);
      float p2 = __expf(ev[k][2] - m);
      float p3 = __expf(ev[k][3] - m);
      s += (p0+p1)+(p2+p3);
      union { bf16 h[4]; uint2 u; } pk;
      pk.h[0]=(bf16)p0; pk.h[1]=(bf16)p1; pk.h[2]=(bf16)p2; pk.h[3]=(bf16)p3;
      *(uint2*)(prow + ((k*512 + lane*8) ^ ((r&7)<<4))) = pk.u;
    }
    #pragma unroll
    for (int off = 32; off > 0; off >>= 1) s += __shfl_xor(s, off);
    if (lane == 0) sums[r] = s;
  }
  __syncthreads();
  const int l15 = lane & 15, lh = lane >> 4;
  const bf16* bT = WhT + (size_t)(w*16 + l15)*2048;
  f32x4 ac[4];
  #pragma unroll
  for (int q = 0; q < 4; ++q) ac[q] = (f32x4){0.f,0.f,0.f,0.f};
  for (int kt = 0; kt < 64; kt += 4) {
    #pragma unroll
    for (int q = 0; q < 4; ++q) {
      i32x4 af = *(const i32x4*)((char*)P + l15*4096 + (((kt+q)*64 + lh*16) ^ ((l15&7)<<4)));
      i32x4 bf = *(const i32x4*)(bT + (kt+q)*32 + lh*8);
      ac[q] = mfma16(af, bf, ac[q]);
    }
  }
  f32x4 accv = (ac[0] + ac[1]) + (ac[2] + ac[3]);
  #pragma unroll
  for (int rg = 0; rg < 4; ++rg) {
    int i = i0 + lh*4 + rg;
    float v = accv[rg] / sums[lh*4 + rg];
    if (applyElu) v = (v > 0.f) ? v : (__expf(v) - 1.0f);
    outp[(size_t)i*128 + w*16 + l15] = v;
  }
}

// ---------------- launch ----------------
extern "C" void kernel_launch(void* const* d_in, const int* in_sizes, int n_in,
                              void* d_out, int out_size, void* d_ws, size_t ws_size,
                              hipStream_t stream)
{
  (void)in_sizes; (void)n_in; (void)out_size; (void)ws_size;
  const float* x    = (const float*)d_in[0];
  const int*   adj  = (const int*)d_in[1];
  const float* c1w  = (const float*)d_in[2];
  const float* c1b  = (const float*)d_in[3];
  const float* bn1g = (const float*)d_in[4];
  const float* bn1b = (const float*)d_in[5];
  const float* c2w  = (const float*)d_in[6];
  const float* c2b  = (const float*)d_in[7];
  const float* bn2g = (const float*)d_in[8];
  const float* bn2b = (const float*)d_in[9];
  const float* wif  = (const float*)d_in[10];
  const float* whf  = (const float*)d_in[11];
  const float* bfv  = (const float*)d_in[12];
  const float* wir  = (const float*)d_in[13];
  const float* whr  = (const float*)d_in[14];
  const float* brv  = (const float*)d_in[15];
  const float* g1W  = (const float*)d_in[16];
  const float* g1a  = (const float*)d_in[17];
  const float* g2W  = (const float*)d_in[18];
  const float* g2a  = (const float*)d_in[19];
  float* outp = (float*)d_out;
  float* ws   = (float*)d_ws;

  bf16* y12    = (bf16*)(ws + OFF_A);
  bf16* pool1t = (bf16*)(ws + OFF_B);      // [2048][256][64]
  bf16* pool2t = (bf16*)(ws + OFF_B1);     // [2048][128][128]
  bf16* whh_g  = (bf16*)(ws + OFF_WHHG);
  bf16* wih_g  = (bf16*)(ws + OFF_WIHG);
  float* bias_g= ws + OFF_BIAS;
  float* hsm   = ws + OFF_HSUM;
  float* feats = ws + OFF_FEAT;
  float* Wh1   = ws + OFF_WH1;
  float* s1a   = ws + OFF_S1A;
  float* s2a   = ws + OFF_S2A;
  float* h1    = ws + OFF_H1;
  float* Wh2   = ws + OFF_WH2;
  float* s1b   = ws + OFF_S1B;
  float* s2b   = ws + OFF_S2B;
  float* stat  = ws + OFF_STAT;
  bf16* w1p    = (bf16*)(ws + OFF_W1P);
  bf16* w2p    = (bf16*)(ws + OFF_W2P);
  bf16* whT    = (bf16*)(ws + OFF_WHT);

  hipMemsetAsync(stat, 0, 512*sizeof(float), stream);

  prep_kernel<<<dim3(256,2),256,0,stream>>>(whf, whr, wif, wir, bfv, brv, c1w, c2w,
                                            whh_g, wih_g, bias_g, w1p, w2p);

  // conv1 -> BN -> relu -> pool (+transpose)
  conv1_kernel<<<dim3(2,2048),512,0,stream>>>(x, w1p, c1b, y12);
  bn_stats_kernel<<<dim3(64,32),256,0,stream>>>(y12, stat, 64, 512);
  bn_finalize_kernel<<<1,128,0,stream>>>(stat, bn1g, bn1b, 64, 1.0f/(2048.0f*512.0f));
  poolT_kernel<64,256><<<2048,256,0,stream>>>(y12, stat, pool1t);

  // conv2 -> BN -> relu -> pool (+transpose)
  hipMemsetAsync(stat, 0, 256*sizeof(float), stream);
  conv2_kernel<<<2048,512,0,stream>>>(pool1t, w2p, c2b, y12);
  bn_stats_kernel<<<dim3(128,32),256,0,stream>>>(y12, stat, 128, 256);
  bn_finalize_kernel<<<1,128,0,stream>>>(stat, bn2g, bn2b, 128, 1.0f/(2048.0f*256.0f));
  poolT_kernel<128,128><<<2048,256,0,stream>>>(y12, stat, pool2t);

  // fused biLSTM (8 nodes/block, 2 blocks/CU)
  lstm_fused_kernel<<<512,512,0,stream>>>(pool2t, wih_g, whh_g, bias_g, hsm);
  feats_kernel<<<2048,256,0,stream>>>(hsm, feats);

  // GAT x2
  node_gemm_kernel<256><<<64,256,0,stream>>>(feats, g1W, Wh1, whT);
  gat_s_kernel<<<512,256,0,stream>>>(Wh1, g1a, s1a, s2a);
  gat_attn16_kernel<<<128,512,0,stream>>>(whT, s1a, s2a, adj, h1, 1);
  node_gemm_kernel<128><<<64,256,0,stream>>>(h1, g2W, Wh2, whT);
  gat_s_kernel<<<512,256,0,stream>>>(Wh2, g2a, s1b, s2b);
  gat_attn16_kernel<<<128,512,0,stream>>>(whT, s1b, s2b, adj, outp, 0);
}

// Round 8
// 607.310 us; speedup vs baseline: 3.4742x; 3.4742x over previous
//
#include <hip/hip_runtime.h>

typedef unsigned int uint;
#define DI __device__ __forceinline__

typedef __bf16 bf16;
typedef __attribute__((ext_vector_type(4))) float f32x4;
typedef __attribute__((ext_vector_type(8))) __bf16 bf16x8;
typedef __attribute__((ext_vector_type(4))) int i32x4;

// ---------------- ws layout (float units) ----------------
constexpr size_t OFF_A    = 0;                    // y1/y2 bf16 [N][C][T]
constexpr size_t OFF_B    = 33554432;             // pool1t bf16
constexpr size_t OFF_B1   = OFF_B + 16777216;     // pool2t bf16 [2048][128][128]
constexpr size_t OFF_WHHG = 67108864;             // bf16 [2][512][128]
constexpr size_t OFF_WIHG = OFF_WHHG + 65536;     // bf16 [2][512][128]
constexpr size_t OFF_BIAS = OFF_WIHG + 65536;     // f32 [2][512]
constexpr size_t OFF_HSUM = OFF_BIAS + 1024;      // f32 [2][2048][128]
constexpr size_t OFF_FEAT = OFF_HSUM + 524288;    // f32 [2048][256]
constexpr size_t OFF_WH1  = OFF_FEAT + 524288;    // f32 [2048][128]
constexpr size_t OFF_S1A  = OFF_WH1 + 262144;
constexpr size_t OFF_S2A  = OFF_S1A + 2048;
constexpr size_t OFF_H1   = OFF_S2A + 2048;
constexpr size_t OFF_WH2  = OFF_H1 + 262144;
constexpr size_t OFF_S1B  = OFF_WH2 + 262144;
constexpr size_t OFF_S2B  = OFF_S1B + 2048;
constexpr size_t OFF_STAT = OFF_S2B + 2048;       // sum/sumsq/scale/shift
constexpr size_t OFF_W1P  = OFF_STAT + 512;       // bf16 12288 (pre-swizzled conv1 w)
constexpr size_t OFF_W2P  = OFF_W1P + 6144;       // bf16 24576 (pre-swizzled conv2 w)
constexpr size_t OFF_WHT  = OFF_W2P + 12288;      // bf16 [128][2048] (WhT, reused both layers)

DI float bflo(uint u){ union { uint i; float f; } v; v.i = u << 16;         return v.f; }
DI float bfhi(uint u){ union { uint i; float f; } v; v.i = u & 0xffff0000u; return v.f; }
DI float fexp2_(float x){ return __builtin_amdgcn_exp2f(x); }
DI float frcp_(float x){ return __builtin_amdgcn_rcpf(x); }
DI float sigf_(float x){ return frcp_(1.0f + fexp2_(x * -1.44269504f)); }
// tanh(x) = 1 - 2/(e^{2x}+1); saturates correctly at +/-inf
DI float tanhx_(float x){ return 1.0f - 2.0f*frcp_(1.0f + fexp2_(x * 2.88539009f)); }

DI f32x4 mfma16(i32x4 a, i32x4 b, f32x4 c){
  return __builtin_amdgcn_mfma_f32_16x16x32_bf16(
      __builtin_bit_cast(bf16x8, a), __builtin_bit_cast(bf16x8, b), c, 0, 0, 0);
}

// swizzled LDS address helpers (XOR bits[4:6] by row&7)
DI char* swz128(char* base, int row, int byteInRow){ return base + row*128 + (byteInRow ^ ((row&7)<<4)); }
DI char* swz256(char* base, int row, int byteInRow){ return base + row*256 + (byteInRow ^ ((row&7)<<4)); }

// ---------------- prep: gate-interleaved LSTM weights + pre-swizzled conv weights ----------------
__global__ void prep_kernel(const float* __restrict__ whf, const float* __restrict__ whr,
                            const float* __restrict__ wif, const float* __restrict__ wir,
                            const float* __restrict__ bfv, const float* __restrict__ brv,
                            const float* __restrict__ c1w, const float* __restrict__ c2w,
                            bf16* __restrict__ whh_g, bf16* __restrict__ wih_g,
                            float* __restrict__ bias_g,
                            bf16* __restrict__ w1p, bf16* __restrict__ w2p)
{
  const int dir = blockIdx.y;
  const float* whh = dir ? whr : whf;
  const float* wih = dir ? wir : wif;
  const float* bb  = dir ? brv : bfv;
  int idx = blockIdx.x*256 + threadIdx.x;        // < 65536
  int c = idx >> 7, d = idx & 127;
  int src = ((c & 3)*128 + (c >> 2))*128 + d;
  whh_g[(size_t)dir*65536 + idx] = (bf16)whh[src];
  wih_g[(size_t)dir*65536 + idx] = (bf16)wih[src];
  if (idx < 512) bias_g[dir*512 + idx] = bb[(idx & 3)*128 + (idx >> 2)];
  if (dir == 0) {
    if (idx < 12288) {
      int row = idx >> 6;
      int ci = (((idx & 63)*2) ^ ((row & 7) << 4)) >> 1;
      int co = row & 63, dk = row >> 6;
      w1p[idx] = (bf16)c1w[(co*64 + ci)*3 + dk];
    }
    if (idx < 24576) {
      int row = idx >> 6;
      int ci = (((idx & 63)*2) ^ ((row & 7) << 4)) >> 1;
      int co = row & 127, dk = row >> 7;
      w2p[idx] = (bf16)c2w[(co*64 + ci)*3 + dk];
    }
  }
}

// ---------------- conv1: x f32 [2048][64][512] -> y1 bf16 [2048][64][512] ----------------
__global__ __launch_bounds__(512) void conv1_kernel(
    const float* __restrict__ x, const bf16* __restrict__ w1p,
    const float* __restrict__ bias, bf16* __restrict__ y)
{
  __shared__ bf16 xa[258*64];     // [row=t-t0+1][ci], 128B rows, swizzled
  __shared__ bf16 wb[3*64*64];    // [dk*64+co][ci], swizzled (pre-swizzled copy)
  const int n = blockIdx.y, t0 = blockIdx.x*256, tid = threadIdx.x;
  {
    const i32x4* wsrc = (const i32x4*)w1p;
    for (int i = tid; i < 1536; i += 512) ((i32x4*)wb)[i] = wsrc[i];
  }
  for (int i = tid; i < 2048; i += 512) {
    int q = i & 63, cp = i >> 6;          // cp = ci/2
    int ci = cp*2;
    const float* xb = &x[((size_t)n*64 + ci)*512 + t0 + q*4];
    float4 v0 = *(const float4*)xb;
    float4 v1 = *(const float4*)(xb + 512);
    int row = q*4 + 1;
    union { bf16 h[2]; uint u; } p0, p1, p2, p3;
    p0.h[0]=(bf16)v0.x; p0.h[1]=(bf16)v1.x;
    p1.h[0]=(bf16)v0.y; p1.h[1]=(bf16)v1.y;
    p2.h[0]=(bf16)v0.z; p2.h[1]=(bf16)v1.z;
    p3.h[0]=(bf16)v0.w; p3.h[1]=(bf16)v1.w;
    *(uint*)swz128((char*)xa, row+0, ci*2) = p0.u;
    *(uint*)swz128((char*)xa, row+1, ci*2) = p1.u;
    *(uint*)swz128((char*)xa, row+2, ci*2) = p2.u;
    *(uint*)swz128((char*)xa, row+3, ci*2) = p3.u;
  }
  if (tid < 128) {
    int ci = tid >> 1, e = tid & 1;
    int row = e ? 257 : 0;
    int t = t0 + (e ? 256 : -1);
    float v = (t >= 0 && t < 512) ? x[((size_t)n*64 + ci)*512 + t] : 0.0f;
    *(bf16*)swz128((char*)xa, row, ci*2) = (bf16)v;
  }
  __syncthreads();
  const int lane = tid & 63, wv = tid >> 6;
  const int m0 = (wv & 3)*64, c0 = (wv >> 2)*32;
  const int l15 = lane & 15, lh = lane >> 4;
  f32x4 acc[4][2];
  #pragma unroll
  for (int mf = 0; mf < 4; ++mf)
    #pragma unroll
    for (int cf = 0; cf < 2; ++cf) {
      float bb = bias[c0 + cf*16 + l15];
      acc[mf][cf] = (f32x4){bb, bb, bb, bb};
    }
  #pragma unroll
  for (int dk = 0; dk < 3; ++dk)
    #pragma unroll
    for (int ks = 0; ks < 2; ++ks) {
      const int kb = ks*64 + lh*16;
      i32x4 bfr[2], afr[4];
      #pragma unroll
      for (int cf = 0; cf < 2; ++cf) {
        int row = dk*64 + c0 + cf*16 + l15;
        bfr[cf] = *(const i32x4*)swz128((char*)wb, row, kb);
      }
      #pragma unroll
      for (int mf = 0; mf < 4; ++mf) {
        int row = m0 + mf*16 + l15 + dk;
        afr[mf] = *(const i32x4*)swz128((char*)xa, row, kb);
      }
      #pragma unroll
      for (int mf = 0; mf < 4; ++mf)
        #pragma unroll
        for (int cf = 0; cf < 2; ++cf)
          acc[mf][cf] = mfma16(afr[mf], bfr[cf], acc[mf][cf]);
    }
  #pragma unroll
  for (int mf = 0; mf < 4; ++mf)
    #pragma unroll
    for (int cf = 0; cf < 2; ++cf) {
      int co = c0 + cf*16 + l15;
      int tt = t0 + m0 + mf*16 + lh*4;
      union { bf16 h[4]; uint2 u; } pk;
      #pragma unroll
      for (int r = 0; r < 4; ++r) pk.h[r] = (bf16)acc[mf][cf][r];
      *(uint2*)&y[((size_t)n*64 + co)*512 + tt] = pk.u;
    }
}

// ---------------- conv2: pool1T bf16 [2048][256][64] -> y2 bf16 [2048][128][256] ----------------
__global__ __launch_bounds__(512) void conv2_kernel(
    const bf16* __restrict__ xin, const bf16* __restrict__ w2p,
    const float* __restrict__ bias, bf16* __restrict__ y)
{
  __shared__ bf16 xa[258*64];
  __shared__ bf16 wb[3*128*64];
  const int n = blockIdx.x, tid = threadIdx.x;
  {
    const i32x4* wsrc = (const i32x4*)w2p;
    for (int i = tid; i < 3072; i += 512) ((i32x4*)wb)[i] = wsrc[i];
  }
  {
    const i32x4* src = (const i32x4*)(xin + (size_t)n*256*64);
    for (int i = tid; i < 2048; i += 512) {
      int row = (i >> 3) + 1, blk = i & 7;
      *(i32x4*)swz128((char*)xa, row, blk*16) = src[i];
    }
  }
  if (tid < 128) {
    int ci = tid >> 1, e = tid & 1;
    int row = e ? 257 : 0;
    *(bf16*)swz128((char*)xa, row, ci*2) = (bf16)0.0f;
  }
  __syncthreads();
  const int lane = tid & 63, wv = tid >> 6;
  const int m0 = (wv & 3)*64, c0 = (wv >> 2)*64;
  const int l15 = lane & 15, lh = lane >> 4;
  f32x4 acc[4][4];
  #pragma unroll
  for (int mf = 0; mf < 4; ++mf)
    #pragma unroll
    for (int cf = 0; cf < 4; ++cf) {
      float bb = bias[c0 + cf*16 + l15];
      acc[mf][cf] = (f32x4){bb, bb, bb, bb};
    }
  #pragma unroll
  for (int dk = 0; dk < 3; ++dk)
    #pragma unroll
    for (int ks = 0; ks < 2; ++ks) {
      const int kb = ks*64 + lh*16;
      i32x4 bfr[4], afr[4];
      #pragma unroll
      for (int cf = 0; cf < 4; ++cf) {
        int row = dk*128 + c0 + cf*16 + l15;
        bfr[cf] = *(const i32x4*)swz128((char*)wb, row, kb);
      }
      #pragma unroll
      for (int mf = 0; mf < 4; ++mf) {
        int row = m0 + mf*16 + l15 + dk;
        afr[mf] = *(const i32x4*)swz128((char*)xa, row, kb);
      }
      #pragma unroll
      for (int mf = 0; mf < 4; ++mf)
        #pragma unroll
        for (int cf = 0; cf < 4; ++cf)
          acc[mf][cf] = mfma16(afr[mf], bfr[cf], acc[mf][cf]);
    }
  #pragma unroll
  for (int mf = 0; mf < 4; ++mf)
    #pragma unroll
    for (int cf = 0; cf < 4; ++cf) {
      int co = c0 + cf*16 + l15;
      int tt = m0 + mf*16 + lh*4;
      union { bf16 h[4]; uint2 u; } pk;
      #pragma unroll
      for (int r = 0; r < 4; ++r) pk.h[r] = (bf16)acc[mf][cf][r];
      *(uint2*)&y[((size_t)n*128 + co)*256 + tt] = pk.u;
    }
}

// ---------------- BN stats (vectorized uint4 loads) ----------------
__global__ __launch_bounds__(256) void bn_stats_kernel(
    const bf16* __restrict__ y, float* __restrict__ stat, int C, int T)
{
  const int c = blockIdx.x, n0 = blockIdx.y*64, tid = threadIdx.x;
  float s = 0.f, q = 0.f;
  const int qpr = T >> 3;           // uint4 (8 bf16) per row
  for (int i = tid; i < 64*qpr; i += 256) {
    int n = n0 + i/qpr, qd = i & (qpr - 1);
    uint4 u = *(const uint4*)&y[((size_t)n*C + c)*T + qd*8];
    float v0 = bflo(u.x), v1 = bfhi(u.x), v2 = bflo(u.y), v3 = bfhi(u.y);
    float v4 = bflo(u.z), v5 = bfhi(u.z), v6 = bflo(u.w), v7 = bfhi(u.w);
    s += (v0+v1)+(v2+v3)+((v4+v5)+(v6+v7));
    q += (v0*v0+v1*v1)+(v2*v2+v3*v3)+((v4*v4+v5*v5)+(v6*v6+v7*v7));
  }
  __shared__ float rs[256], rq[256];
  rs[tid] = s; rq[tid] = q; __syncthreads();
  for (int off = 128; off > 0; off >>= 1) {
    if (tid < off) { rs[tid] += rs[tid+off]; rq[tid] += rq[tid+off]; }
    __syncthreads();
  }
  if (tid == 0) { atomicAdd(&stat[c], rs[0]); atomicAdd(&stat[128+c], rq[0]); }
}

__global__ void bn_finalize_kernel(float* __restrict__ stat, const float* __restrict__ g,
                                   const float* __restrict__ b, int C, float invCnt)
{
  int c = threadIdx.x;
  if (c < C) {
    float m  = stat[c]*invCnt;
    float v  = stat[128+c]*invCnt - m*m;
    float sc = g[c]*rsqrtf(v + 1e-5f);
    stat[256+c] = sc;
    stat[384+c] = b[c] - m*sc;
  }
}

// ---------------- BN apply + ReLU + maxpool2 + transpose ----------------
template<int C, int TH>
__global__ __launch_bounds__(256) void poolT_kernel(
    const bf16* __restrict__ yin, const float* __restrict__ stat, bf16* __restrict__ outp)
{
  __shared__ bf16 buf[C][TH + 2];
  const int n = blockIdx.x, tid = threadIdx.x;
  const uint* src = (const uint*)(yin + (size_t)n*C*TH*2);
  for (int i = tid; i < C*TH; i += 256) {
    int th = i & (TH - 1), c = i / TH;
    uint u = src[i];
    float sc = stat[256 + c], sh = stat[384 + c];
    float a = fmaxf(sc*bflo(u) + sh, 0.f);
    float b = fmaxf(sc*bfhi(u) + sh, 0.f);
    buf[c][th] = (bf16)fmaxf(a, b);
  }
  __syncthreads();
  bf16* dst = outp + (size_t)n*TH*C;
  for (int i = tid; i < TH*C/2; i += 256) {
    int cp = i & (C/2 - 1), th = i / (C/2);
    union { bf16 h[2]; uint u; } pk;
    pk.h[0] = buf[2*cp][th]; pk.h[1] = buf[2*cp + 1][th];
    *(uint*)&dst[th*C + 2*cp] = pk.u;
  }
}

// ---------------- fused biLSTM (proven R5 config): 16 nodes/block, 8 waves ----------------
// grid 256 = (128 node-groups x 2 dirs), block 512 = 8 waves; wave wv owns gate-cols
// [wv*64, wv*64+64). mfma16(weight, x/h): col=node=lane&15, row = gates i,f,g,o of
// (node=l15, hh=wv*16+cf*4+lh). h double-buffered in 8KB LDS; 1 barrier/t.
__global__ __launch_bounds__(512, 2) void lstm_fused_kernel(
    const bf16* __restrict__ p2t, const bf16* __restrict__ wih_g,
    const bf16* __restrict__ whh_g, const float* __restrict__ bias_g,
    float* __restrict__ hsum)
{
  __shared__ bf16 hb[2][2048];   // [buf][16 n][128 hh], 256B rows, swizzled
  const int z = blockIdx.x;
  const int dir = z & 1, n0 = (z >> 1)*16;
  const int tid = threadIdx.x, lane = tid & 63, wv = tid >> 6;
  const int l15 = lane & 15, lh = lane >> 4;
  i32x4 wihr[4][4], whhr[4][4];
  {
    const bf16* wi = wih_g + (size_t)dir*65536;
    const bf16* wh = whh_g + (size_t)dir*65536;
    #pragma unroll
    for (int cf = 0; cf < 4; ++cf) {
      int c = wv*64 + cf*16 + l15;
      #pragma unroll
      for (int ks = 0; ks < 4; ++ks) {
        wihr[cf][ks] = *(const i32x4*)(wi + (size_t)c*128 + ks*32 + lh*8);
        whhr[cf][ks] = *(const i32x4*)(wh + (size_t)c*128 + ks*32 + lh*8);
      }
    }
  }
  f32x4 bias4[4];
  #pragma unroll
  for (int cf = 0; cf < 4; ++cf) {
    int hh = wv*16 + cf*4 + lh;
    bias4[cf] = *(const f32x4*)&bias_g[dir*512 + hh*4];
  }
  for (int i = tid; i < 256; i += 512) ((i32x4*)hb[0])[i] = (i32x4){0,0,0,0};
  const bf16* xrow = p2t + (size_t)(n0 + l15)*128*128;
  float creg[4] = {0.f,0.f,0.f,0.f}, hac[4] = {0.f,0.f,0.f,0.f};
  f32x4 acc[4];
  i32x4 xn[4];
  { // prologue: acc = bias + x(t=0) @ wih
    int ts0 = dir ? 127 : 0;
    #pragma unroll
    for (int ks = 0; ks < 4; ++ks)
      xn[ks] = *(const i32x4*)(xrow + (size_t)ts0*128 + ks*32 + lh*8);
    #pragma unroll
    for (int cf = 0; cf < 4; ++cf) {
      acc[cf] = mfma16(wihr[cf][0], xn[0], bias4[cf]);
      #pragma unroll
      for (int ks = 1; ks < 4; ++ks)
        acc[cf] = mfma16(wihr[cf][ks], xn[ks], acc[cf]);
    }
  }
  int cur = 0;
  __syncthreads();
  for (int t = 0; t < 128; ++t) {
    { // load x(t+1) early (consumed after nonlin)
      int tn = (t + 1 < 128) ? t + 1 : 127;
      int tsn = dir ? 127 - tn : tn;
      #pragma unroll
      for (int ks = 0; ks < 4; ++ks)
        xn[ks] = *(const i32x4*)(xrow + (size_t)tsn*128 + ks*32 + lh*8);
    }
    // recurrence: acc += h(t-1) @ whh
    {
      i32x4 a0 = *(const i32x4*)swz256((char*)hb[cur], l15, 0*64 + lh*16);
      i32x4 a1 = *(const i32x4*)swz256((char*)hb[cur], l15, 1*64 + lh*16);
      #pragma unroll
      for (int cf = 0; cf < 4; ++cf) {
        acc[cf] = mfma16(whhr[cf][0], a0, acc[cf]);
        acc[cf] = mfma16(whhr[cf][1], a1, acc[cf]);
      }
      a0 = *(const i32x4*)swz256((char*)hb[cur], l15, 2*64 + lh*16);
      a1 = *(const i32x4*)swz256((char*)hb[cur], l15, 3*64 + lh*16);
      #pragma unroll
      for (int cf = 0; cf < 4; ++cf) {
        acc[cf] = mfma16(whhr[cf][2], a0, acc[cf]);
        acc[cf] = mfma16(whhr[cf][3], a1, acc[cf]);
      }
    }
    // nonlinearity: regs = gates i,f,g,o directly
    #pragma unroll
    for (int cf = 0; cf < 4; ++cf) {
      float ig = sigf_(acc[cf][0]);
      float fg = sigf_(acc[cf][1]);
      float gg = tanhx_(acc[cf][2]);
      float og = sigf_(acc[cf][3]);
      float cv = fg*creg[cf] + ig*gg;
      creg[cf] = cv;
      float hv = og*tanhx_(cv);
      hac[cf] += hv;
      int hh = wv*16 + cf*4 + lh;
      *(bf16*)swz256((char*)hb[cur^1], l15, hh*2) = (bf16)hv;
    }
    // inproj for t+1 (independent of h; overlaps VALU of other wave / barrier)
    #pragma unroll
    for (int cf = 0; cf < 4; ++cf) {
      acc[cf] = mfma16(wihr[cf][0], xn[0], bias4[cf]);
      #pragma unroll
      for (int ks = 1; ks < 4; ++ks)
        acc[cf] = mfma16(wihr[cf][ks], xn[ks], acc[cf]);
    }
    __syncthreads();
    cur ^= 1;
  }
  float* hm = hsum + ((size_t)dir*2048 + n0)*128;
  #pragma unroll
  for (int cf = 0; cf < 4; ++cf) {
    int hh = wv*16 + cf*4 + lh;
    hm[(size_t)l15*128 + hh] = hac[cf];
  }
}

// ---------------- feats = mean over T of [hf, hr] ----------------
__global__ __launch_bounds__(256) void feats_kernel(const float* __restrict__ hsum, float* __restrict__ feats)
{
  int idx = blockIdx.x*256 + threadIdx.x;
  int k = idx & 255, n = idx >> 8;
  float v = (k < 128) ? hsum[(size_t)n*128 + k]
                      : hsum[(size_t)2048*128 + (size_t)n*128 + (k - 128)];
  feats[idx] = v * 0.0078125f;
}

// ---------------- Wh = in @ W^T  ([2048,K] x [128,K]); also emits WhT bf16 [128][2048] ----------------
template<int K>
__global__ __launch_bounds__(256) void node_gemm_kernel(
    const float* __restrict__ inp, const float* __restrict__ W,
    float* __restrict__ outp, bf16* __restrict__ outT)
{
  __shared__ float ft[32][K];
  const int i0 = blockIdx.x*32, tid = threadIdx.x;
  for (int i = tid; i < 32*K; i += 256) ft[i/K][i%K] = inp[(size_t)i0*K + i];
  __syncthreads();
  const int f = tid & 127, ih = (tid >> 7)*16;
  float acc[16];
  #pragma unroll
  for (int ii = 0; ii < 16; ++ii) acc[ii] = 0.f;
  const float* wp = W + (size_t)f*K;
  for (int k = 0; k < K; k += 4) {
    const float4 wv = *reinterpret_cast<const float4*>(&wp[k]);
    #pragma unroll
    for (int ii = 0; ii < 16; ++ii) {
      const float* fp = &ft[ih+ii][k];
      acc[ii] += fp[0]*wv.x + fp[1]*wv.y + fp[2]*wv.z + fp[3]*wv.w;
    }
  }
  union { bf16 h[16]; uint4 u[2]; } pk;
  #pragma unroll
  for (int ii = 0; ii < 16; ++ii) {
    outp[(size_t)(i0+ih+ii)*128 + f] = acc[ii];
    pk.h[ii] = (bf16)acc[ii];
  }
  uint4* dT = (uint4*)&outT[(size_t)f*2048 + i0 + ih];
  dT[0] = pk.u[0]; dT[1] = pk.u[1];
}

// ---------------- s1/s2 per node ----------------
__global__ __launch_bounds__(256) void gat_s_kernel(const float* __restrict__ Wh,
    const float* __restrict__ a, float* __restrict__ s1, float* __restrict__ s2)
{
  const int node = blockIdx.x*4 + (threadIdx.x >> 6);
  const int l = threadIdx.x & 63;
  const float w0 = Wh[(size_t)node*128 + l], w1 = Wh[(size_t)node*128 + 64 + l];
  float v1 = w0*a[l]     + w1*a[64+l];
  float v2 = w0*a[128+l] + w1*a[192+l];
  #pragma unroll
  for (int off = 32; off > 0; off >>= 1) { v1 += __shfl_down(v1, off); v2 += __shfl_down(v2, off); }
  if (l == 0) { s1[node] = v1; s2[node] = v2; }
}

// ---------------- GAT attention, 16 rows/block, MFMA aggregation ----------------
__global__ __launch_bounds__(512) void gat_attn16_kernel(
    const bf16* __restrict__ WhT,
    const float* __restrict__ s1, const float* __restrict__ s2v,
    const int* __restrict__ adj, float* __restrict__ outp, int applyElu)
{
  __shared__ bf16 P[16*2048];     // rows of 4096B, swizzled
  __shared__ float sums[16];
  const int i0 = blockIdx.x*16, tid = threadIdx.x;
  const int lane = tid & 63, w = tid >> 6;
  for (int rr = 0; rr < 2; ++rr) {
    const int r = w*2 + rr, i = i0 + r;
    const float s1i = s1[i];
    const int4* arow = (const int4*)(adj + (size_t)i*2048);
    float ev[8][4];
    float m = -3.0e38f;
    #pragma unroll
    for (int k = 0; k < 8; ++k) {
      int4 ad = arow[k*64 + lane];
      float4 sv = *(const float4*)&s2v[k*256 + lane*4];
      float e0 = s1i + sv.x; e0 = (e0 > 0.f) ? e0 : 0.2f*e0; e0 = (ad.x > 0) ? e0 : -3.0e38f;
      float e1 = s1i + sv.y; e1 = (e1 > 0.f) ? e1 : 0.2f*e1; e1 = (ad.y > 0) ? e1 : -3.0e38f;
      float e2 = s1i + sv.z; e2 = (e2 > 0.f) ? e2 : 0.2f*e2; e2 = (ad.z > 0) ? e2 : -3.0e38f;
      float e3 = s1i + sv.w; e3 = (e3 > 0.f) ? e3 : 0.2f*e3; e3 = (ad.w > 0) ? e3 : -3.0e38f;
      ev[k][0]=e0; ev[k][1]=e1; ev[k][2]=e2; ev[k][3]=e3;
      m = fmaxf(m, fmaxf(fmaxf(e0,e1), fmaxf(e2,e3)));
    }
    #pragma unroll
    for (int off = 32; off > 0; off >>= 1) m = fmaxf(m, __shfl_xor(m, off));
    float s = 0.f;
    char* prow = (char*)P + r*4096;
    #pragma unroll
    for (int k = 0; k < 8; ++k) {
      float p0 = __expf(ev[k][0] - m);
      float p1 = __expf(ev[k][1] - m);
      float p2 = __expf(ev[k][2] - m);
      float p3 = __expf(ev[k][3] - m);
      s += (p0+p1)+(p2+p3);
      union { bf16 h[4]; uint2 u; } pk;
      pk.h[0]=(bf16)p0; pk.h[1]=(bf16)p1; pk.h[2]=(bf16)p2; pk.h[3]=(bf16)p3;
      *(uint2*)(prow + ((k*512 + lane*8) ^ ((r&7)<<4))) = pk.u;
    }
    #pragma unroll
    for (int off = 32; off > 0; off >>= 1) s += __shfl_xor(s, off);
    if (lane == 0) sums[r] = s;
  }
  __syncthreads();
  const int l15 = lane & 15, lh = lane >> 4;
  const bf16* bT = WhT + (size_t)(w*16 + l15)*2048;
  f32x4 ac[4];
  #pragma unroll
  for (int q = 0; q < 4; ++q) ac[q] = (f32x4){0.f,0.f,0.f,0.f};
  for (int kt = 0; kt < 64; kt += 4) {
    #pragma unroll
    for (int q = 0; q < 4; ++q) {
      i32x4 af = *(const i32x4*)((char*)P + l15*4096 + (((kt+q)*64 + lh*16) ^ ((l15&7)<<4)));
      i32x4 bf = *(const i32x4*)(bT + (kt+q)*32 + lh*8);
      ac[q] = mfma16(af, bf, ac[q]);
    }
  }
  f32x4 accv = (ac[0] + ac[1]) + (ac[2] + ac[3]);
  #pragma unroll
  for (int rg = 0; rg < 4; ++rg) {
    int i = i0 + lh*4 + rg;
    float v = accv[rg] / sums[lh*4 + rg];
    if (applyElu) v = (v > 0.f) ? v : (__expf(v) - 1.0f);
    outp[(size_t)i*128 + w*16 + l15] = v;
  }
}

// ---------------- launch ----------------
extern "C" void kernel_launch(void* const* d_in, const int* in_sizes, int n_in,
                              void* d_out, int out_size, void* d_ws, size_t ws_size,
                              hipStream_t stream)
{
  (void)in_sizes; (void)n_in; (void)out_size; (void)ws_size;
  const float* x    = (const float*)d_in[0];
  const int*   adj  = (const int*)d_in[1];
  const float* c1w  = (const float*)d_in[2];
  const float* c1b  = (const float*)d_in[3];
  const float* bn1g = (const float*)d_in[4];
  const float* bn1b = (const float*)d_in[5];
  const float* c2w  = (const float*)d_in[6];
  const float* c2b  = (const float*)d_in[7];
  const float* bn2g = (const float*)d_in[8];
  const float* bn2b = (const float*)d_in[9];
  const float* wif  = (const float*)d_in[10];
  const float* whf  = (const float*)d_in[11];
  const float* bfv  = (const float*)d_in[12];
  const float* wir  = (const float*)d_in[13];
  const float* whr  = (const float*)d_in[14];
  const float* brv  = (const float*)d_in[15];
  const float* g1W  = (const float*)d_in[16];
  const float* g1a  = (const float*)d_in[17];
  const float* g2W  = (const float*)d_in[18];
  const float* g2a  = (const float*)d_in[19];
  float* outp = (float*)d_out;
  float* ws   = (float*)d_ws;

  bf16* y12    = (bf16*)(ws + OFF_A);
  bf16* pool1t = (bf16*)(ws + OFF_B);      // [2048][256][64]
  bf16* pool2t = (bf16*)(ws + OFF_B1);     // [2048][128][128]
  bf16* whh_g  = (bf16*)(ws + OFF_WHHG);
  bf16* wih_g  = (bf16*)(ws + OFF_WIHG);
  float* bias_g= ws + OFF_BIAS;
  float* hsm   = ws + OFF_HSUM;
  float* feats = ws + OFF_FEAT;
  float* Wh1   = ws + OFF_WH1;
  float* s1a   = ws + OFF_S1A;
  float* s2a   = ws + OFF_S2A;
  float* h1    = ws + OFF_H1;
  float* Wh2   = ws + OFF_WH2;
  float* s1b   = ws + OFF_S1B;
  float* s2b   = ws + OFF_S2B;
  float* stat  = ws + OFF_STAT;
  bf16* w1p    = (bf16*)(ws + OFF_W1P);
  bf16* w2p    = (bf16*)(ws + OFF_W2P);
  bf16* whT    = (bf16*)(ws + OFF_WHT);

  hipMemsetAsync(stat, 0, 512*sizeof(float), stream);

  prep_kernel<<<dim3(256,2),256,0,stream>>>(whf, whr, wif, wir, bfv, brv, c1w, c2w,
                                            whh_g, wih_g, bias_g, w1p, w2p);

  // conv1 -> BN -> relu -> pool (+transpose)
  conv1_kernel<<<dim3(2,2048),512,0,stream>>>(x, w1p, c1b, y12);
  bn_stats_kernel<<<dim3(64,32),256,0,stream>>>(y12, stat, 64, 512);
  bn_finalize_kernel<<<1,128,0,stream>>>(stat, bn1g, bn1b, 64, 1.0f/(2048.0f*512.0f));
  poolT_kernel<64,256><<<2048,256,0,stream>>>(y12, stat, pool1t);

  // conv2 -> BN -> relu -> pool (+transpose)
  hipMemsetAsync(stat, 0, 256*sizeof(float), stream);
  conv2_kernel<<<2048,512,0,stream>>>(pool1t, w2p, c2b, y12);
  bn_stats_kernel<<<dim3(128,32),256,0,stream>>>(y12, stat, 128, 256);
  bn_finalize_kernel<<<1,128,0,stream>>>(stat, bn2g, bn2b, 128, 1.0f/(2048.0f*256.0f));
  poolT_kernel<128,128><<<2048,256,0,stream>>>(y12, stat, pool2t);

  // fused biLSTM (single dispatch, proven R5 config)
  lstm_fused_kernel<<<256,512,0,stream>>>(pool2t, wih_g, whh_g, bias_g, hsm);
  feats_kernel<<<2048,256,0,stream>>>(hsm, feats);

  // GAT x2
  node_gemm_kernel<256><<<64,256,0,stream>>>(feats, g1W, Wh1, whT);
  gat_s_kernel<<<512,256,0,stream>>>(Wh1, g1a, s1a, s2a);
  gat_attn16_kernel<<<128,512,0,stream>>>(whT, s1a, s2a, adj, h1, 1);
  node_gemm_kernel<128><<<64,256,0,stream>>>(h1, g2W, Wh2, whT);
  gat_s_kernel<<<512,256,0,stream>>>(Wh2, g2a, s1b, s2b);
  gat_attn16_kernel<<<128,512,0,stream>>>(whT, s1b, s2b, adj, outp, 0);
}

// Round 9
// 558.632 us; speedup vs baseline: 3.7770x; 1.0871x over previous
//
#include <hip/hip_runtime.h>

typedef unsigned int uint;
#define DI __device__ __forceinline__

typedef __bf16 bf16;
typedef __attribute__((ext_vector_type(4))) float f32x4;
typedef __attribute__((ext_vector_type(8))) __bf16 bf16x8;
typedef __attribute__((ext_vector_type(4))) int i32x4;

// ---------------- ws layout (float units) ----------------
constexpr size_t OFF_A    = 0;                    // y1/y2 bf16 [N][C][T]
constexpr size_t OFF_B    = 33554432;             // pool1t bf16
constexpr size_t OFF_B1   = OFF_B + 16777216;     // pool2t bf16 [2048][128][128]
constexpr size_t OFF_WHHG = 67108864;             // bf16 [2][512][128]
constexpr size_t OFF_WIHG = OFF_WHHG + 65536;     // bf16 [2][512][128]
constexpr size_t OFF_BIAS = OFF_WIHG + 65536;     // f32 [2][512]
constexpr size_t OFF_HSUM = OFF_BIAS + 1024;      // f32 [2][2048][128]
constexpr size_t OFF_FEAT = OFF_HSUM + 524288;    // f32 [2048][256]
constexpr size_t OFF_WH1  = OFF_FEAT + 524288;    // f32 [2048][128]
constexpr size_t OFF_S1A  = OFF_WH1 + 262144;
constexpr size_t OFF_S2A  = OFF_S1A + 2048;
constexpr size_t OFF_H1   = OFF_S2A + 2048;
constexpr size_t OFF_WH2  = OFF_H1 + 262144;
constexpr size_t OFF_S1B  = OFF_WH2 + 262144;
constexpr size_t OFF_S2B  = OFF_S1B + 2048;
constexpr size_t OFF_STAT = OFF_S2B + 2048;       // scale/shift live in [256..511]
constexpr size_t OFF_W1P  = OFF_STAT + 512;       // bf16 12288 (pre-swizzled conv1 w)
constexpr size_t OFF_W2P  = OFF_W1P + 6144;       // bf16 24576 (pre-swizzled conv2 w)
constexpr size_t OFF_WHT  = OFF_W2P + 12288;      // bf16 [128][2048]
constexpr size_t OFF_STATP= OFF_WHT + 131072;     // f32 [32][256] partial BN sums

DI float bflo(uint u){ union { uint i; float f; } v; v.i = u << 16;         return v.f; }
DI float bfhi(uint u){ union { uint i; float f; } v; v.i = u & 0xffff0000u; return v.f; }
DI float fexp2_(float x){ return __builtin_amdgcn_exp2f(x); }
DI float frcp_(float x){ return __builtin_amdgcn_rcpf(x); }
DI float sigf_(float x){ return frcp_(1.0f + fexp2_(x * -1.44269504f)); }
DI float tanhx_(float x){ return 1.0f - 2.0f*frcp_(1.0f + fexp2_(x * 2.88539009f)); }

DI f32x4 mfma16(i32x4 a, i32x4 b, f32x4 c){
  return __builtin_amdgcn_mfma_f32_16x16x32_bf16(
      __builtin_bit_cast(bf16x8, a), __builtin_bit_cast(bf16x8, b), c, 0, 0, 0);
}

DI char* swz128(char* base, int row, int byteInRow){ return base + row*128 + (byteInRow ^ ((row&7)<<4)); }
DI char* swz256(char* base, int row, int byteInRow){ return base + row*256 + (byteInRow ^ ((row&7)<<4)); }

// ---------------- prep: gate-interleaved LSTM weights + pre-swizzled conv weights ----------------
__global__ void prep_kernel(const float* __restrict__ whf, const float* __restrict__ whr,
                            const float* __restrict__ wif, const float* __restrict__ wir,
                            const float* __restrict__ bfv, const float* __restrict__ brv,
                            const float* __restrict__ c1w, const float* __restrict__ c2w,
                            bf16* __restrict__ whh_g, bf16* __restrict__ wih_g,
                            float* __restrict__ bias_g,
                            bf16* __restrict__ w1p, bf16* __restrict__ w2p)
{
  const int dir = blockIdx.y;
  const float* whh = dir ? whr : whf;
  const float* wih = dir ? wir : wif;
  const float* bb  = dir ? brv : bfv;
  int idx = blockIdx.x*256 + threadIdx.x;        // < 65536
  int c = idx >> 7, d = idx & 127;
  int src = ((c & 3)*128 + (c >> 2))*128 + d;
  whh_g[(size_t)dir*65536 + idx] = (bf16)whh[src];
  wih_g[(size_t)dir*65536 + idx] = (bf16)wih[src];
  if (idx < 512) bias_g[dir*512 + idx] = bb[(idx & 3)*128 + (idx >> 2)];
  if (dir == 0) {
    if (idx < 12288) {
      int row = idx >> 6;
      int ci = (((idx & 63)*2) ^ ((row & 7) << 4)) >> 1;
      int co = row & 63, dk = row >> 6;
      w1p[idx] = (bf16)c1w[(co*64 + ci)*3 + dk];
    }
    if (idx < 24576) {
      int row = idx >> 6;
      int ci = (((idx & 63)*2) ^ ((row & 7) << 4)) >> 1;
      int co = row & 127, dk = row >> 7;
      w2p[idx] = (bf16)c2w[(co*64 + ci)*3 + dk];
    }
  }
}

// ---------------- conv1 (persistent, double-buffered): 256 blocks x 8 n x 2 t-tiles ----------------
// + fused BN partial stats (sum, sumsq per channel)
__global__ __launch_bounds__(512) void conv1_kernel(
    const float* __restrict__ x, const bf16* __restrict__ w1p,
    const float* __restrict__ bias, bf16* __restrict__ y, float* __restrict__ statp)
{
  __shared__ bf16 xa[2][16512];   // [buf][row=t-t0+1][ci], 128B rows, swizzled
  __shared__ bf16 wb[12288];
  __shared__ float redS[64], redQ[64];
  const int tid = threadIdx.x, nb = blockIdx.x*8;
  {
    const i32x4* wsrc = (const i32x4*)w1p;
    for (int i = tid; i < 1536; i += 512) ((i32x4*)wb)[i] = wsrc[i];
    if (tid < 64) { redS[tid] = 0.f; redQ[tid] = 0.f; }
  }
  auto stage = [&](int buf, int n, int t0) {
    char* base = (char*)xa[buf];
    for (int i = tid; i < 2048; i += 512) {
      int q = i & 63, cp = i >> 6;
      int ci = cp*2;
      const float* xb = &x[((size_t)n*64 + ci)*512 + t0 + q*4];
      float4 v0 = *(const float4*)xb;
      float4 v1 = *(const float4*)(xb + 512);
      int row = q*4 + 1;
      union { bf16 h[2]; uint u; } p0, p1, p2, p3;
      p0.h[0]=(bf16)v0.x; p0.h[1]=(bf16)v1.x;
      p1.h[0]=(bf16)v0.y; p1.h[1]=(bf16)v1.y;
      p2.h[0]=(bf16)v0.z; p2.h[1]=(bf16)v1.z;
      p3.h[0]=(bf16)v0.w; p3.h[1]=(bf16)v1.w;
      *(uint*)swz128(base, row+0, ci*2) = p0.u;
      *(uint*)swz128(base, row+1, ci*2) = p1.u;
      *(uint*)swz128(base, row+2, ci*2) = p2.u;
      *(uint*)swz128(base, row+3, ci*2) = p3.u;
    }
    if (tid < 128) {
      int ci = tid >> 1, e = tid & 1;
      int row = e ? 257 : 0;
      int t = t0 + (e ? 256 : -1);
      float v = (t >= 0 && t < 512) ? x[((size_t)n*64 + ci)*512 + t] : 0.0f;
      *(bf16*)swz128(base, row, ci*2) = (bf16)v;
    }
  };
  stage(0, nb, 0);
  __syncthreads();
  const int lane = tid & 63, wv = tid >> 6;
  const int m0 = (wv & 3)*64, c0 = (wv >> 2)*32;
  const int l15 = lane & 15, lh = lane >> 4;
  const float bb0 = bias[c0 + l15], bb1 = bias[c0 + 16 + l15];
  float bnS[2] = {0.f,0.f}, bnQ[2] = {0.f,0.f};
  for (int it = 0; it < 16; ++it) {
    const int n = nb + (it >> 1), t0 = (it & 1)*256, buf = it & 1;
    if (it + 1 < 16) stage(buf ^ 1, nb + ((it + 1) >> 1), ((it + 1) & 1)*256);
    char* xb = (char*)xa[buf];
    f32x4 acc[4][2];
    #pragma unroll
    for (int mf = 0; mf < 4; ++mf) {
      acc[mf][0] = (f32x4){bb0, bb0, bb0, bb0};
      acc[mf][1] = (f32x4){bb1, bb1, bb1, bb1};
    }
    #pragma unroll
    for (int dk = 0; dk < 3; ++dk)
      #pragma unroll
      for (int ks = 0; ks < 2; ++ks) {
        const int kb = ks*64 + lh*16;
        i32x4 bfr[2], afr[4];
        #pragma unroll
        for (int cf = 0; cf < 2; ++cf) {
          int row = dk*64 + c0 + cf*16 + l15;
          bfr[cf] = *(const i32x4*)swz128((char*)wb, row, kb);
        }
        #pragma unroll
        for (int mf = 0; mf < 4; ++mf) {
          int row = m0 + mf*16 + l15 + dk;
          afr[mf] = *(const i32x4*)swz128(xb, row, kb);
        }
        #pragma unroll
        for (int mf = 0; mf < 4; ++mf)
          #pragma unroll
          for (int cf = 0; cf < 2; ++cf)
            acc[mf][cf] = mfma16(afr[mf], bfr[cf], acc[mf][cf]);
      }
    #pragma unroll
    for (int mf = 0; mf < 4; ++mf)
      #pragma unroll
      for (int cf = 0; cf < 2; ++cf) {
        int co = c0 + cf*16 + l15;
        int tt = t0 + m0 + mf*16 + lh*4;
        union { bf16 h[4]; uint2 u; } pk;
        #pragma unroll
        for (int r = 0; r < 4; ++r) {
          float v = acc[mf][cf][r];
          pk.h[r] = (bf16)v;
          bnS[cf] += v; bnQ[cf] += v*v;
        }
        *(uint2*)&y[((size_t)n*64 + co)*512 + tt] = pk.u;
      }
    __syncthreads();
  }
  atomicAdd(&redS[c0 + l15], bnS[0]);      atomicAdd(&redQ[c0 + l15], bnQ[0]);
  atomicAdd(&redS[c0 + 16 + l15], bnS[1]); atomicAdd(&redQ[c0 + 16 + l15], bnQ[1]);
  __syncthreads();
  if (tid < 64) {
    float* row = statp + (size_t)(blockIdx.x & 31)*256;
    atomicAdd(&row[tid], redS[tid]);
    atomicAdd(&row[128 + tid], redQ[tid]);
  }
}

// ---------------- conv2 (persistent, double-buffered): 256 blocks x 8 n ----------------
__global__ __launch_bounds__(512) void conv2_kernel(
    const bf16* __restrict__ xin, const bf16* __restrict__ w2p,
    const float* __restrict__ bias, bf16* __restrict__ y, float* __restrict__ statp)
{
  __shared__ bf16 xa[2][16512];
  __shared__ bf16 wb[24576];
  __shared__ float redS[128], redQ[128];
  const int tid = threadIdx.x, nb = blockIdx.x*8;
  {
    const i32x4* wsrc = (const i32x4*)w2p;
    for (int i = tid; i < 3072; i += 512) ((i32x4*)wb)[i] = wsrc[i];
    if (tid < 128) { redS[tid] = 0.f; redQ[tid] = 0.f; }
    if (tid < 256) {           // zero halo rows 0 and 257 of both buffers (constant)
      int ci = (tid & 127) >> 1, e = tid & 1, buf = tid >> 7;
      int row = e ? 257 : 0;
      *(bf16*)swz128((char*)xa[buf], row, ci*2) = (bf16)0.0f;
    }
  }
  auto stage = [&](int buf, int n) {
    char* base = (char*)xa[buf];
    const i32x4* src = (const i32x4*)(xin + (size_t)n*16384);
    for (int i = tid; i < 2048; i += 512) {
      int row = (i >> 3) + 1, blk = i & 7;
      *(i32x4*)swz128(base, row, blk*16) = src[i];
    }
  };
  stage(0, nb);
  __syncthreads();
  const int lane = tid & 63, wv = tid >> 6;
  const int m0 = (wv & 3)*64, c0 = (wv >> 2)*64;
  const int l15 = lane & 15, lh = lane >> 4;
  float bbv[4];
  #pragma unroll
  for (int cf = 0; cf < 4; ++cf) bbv[cf] = bias[c0 + cf*16 + l15];
  float bnS[4] = {0.f,0.f,0.f,0.f}, bnQ[4] = {0.f,0.f,0.f,0.f};
  for (int it = 0; it < 8; ++it) {
    const int n = nb + it, buf = it & 1;
    if (it + 1 < 8) stage(buf ^ 1, nb + it + 1);
    char* xb = (char*)xa[buf];
    f32x4 acc[4][4];
    #pragma unroll
    for (int mf = 0; mf < 4; ++mf)
      #pragma unroll
      for (int cf = 0; cf < 4; ++cf)
        acc[mf][cf] = (f32x4){bbv[cf], bbv[cf], bbv[cf], bbv[cf]};
    #pragma unroll
    for (int dk = 0; dk < 3; ++dk)
      #pragma unroll
      for (int ks = 0; ks < 2; ++ks) {
        const int kb = ks*64 + lh*16;
        i32x4 bfr[4], afr[4];
        #pragma unroll
        for (int cf = 0; cf < 4; ++cf) {
          int row = dk*128 + c0 + cf*16 + l15;
          bfr[cf] = *(const i32x4*)swz128((char*)wb, row, kb);
        }
        #pragma unroll
        for (int mf = 0; mf < 4; ++mf) {
          int row = m0 + mf*16 + l15 + dk;
          afr[mf] = *(const i32x4*)swz128(xb, row, kb);
        }
        #pragma unroll
        for (int mf = 0; mf < 4; ++mf)
          #pragma unroll
          for (int cf = 0; cf < 4; ++cf)
            acc[mf][cf] = mfma16(afr[mf], bfr[cf], acc[mf][cf]);
      }
    #pragma unroll
    for (int mf = 0; mf < 4; ++mf)
      #pragma unroll
      for (int cf = 0; cf < 4; ++cf) {
        int co = c0 + cf*16 + l15;
        int tt = m0 + mf*16 + lh*4;
        union { bf16 h[4]; uint2 u; } pk;
        #pragma unroll
        for (int r = 0; r < 4; ++r) {
          float v = acc[mf][cf][r];
          pk.h[r] = (bf16)v;
          bnS[cf] += v; bnQ[cf] += v*v;
        }
        *(uint2*)&y[((size_t)n*128 + co)*256 + tt] = pk.u;
      }
    __syncthreads();
  }
  #pragma unroll
  for (int cf = 0; cf < 4; ++cf) {
    int co = c0 + cf*16 + l15;
    atomicAdd(&redS[co], bnS[cf]);
    atomicAdd(&redQ[co], bnQ[cf]);
  }
  __syncthreads();
  if (tid < 128) {
    float* row = statp + (size_t)(blockIdx.x & 31)*256;
    atomicAdd(&row[tid], redS[tid]);
    atomicAdd(&row[128 + tid], redQ[tid]);
  }
}

// ---------------- BN finalize: reduce 32 partial rows -> scale/shift ----------------
__global__ void bn_finalize_kernel(const float* __restrict__ statp, float* __restrict__ stat,
                                   const float* __restrict__ g, const float* __restrict__ b,
                                   int C, float invCnt)
{
  int c = threadIdx.x;
  if (c < C) {
    float s = 0.f, q = 0.f;
    for (int r = 0; r < 32; ++r) { s += statp[r*256 + c]; q += statp[r*256 + 128 + c]; }
    float m  = s*invCnt;
    float v  = q*invCnt - m*m;
    float sc = g[c]*rsqrtf(v + 1e-5f);
    stat[256+c] = sc;
    stat[384+c] = b[c] - m*sc;
  }
}

// ---------------- BN apply + ReLU + maxpool2 + transpose ----------------
template<int C, int TH>
__global__ __launch_bounds__(256) void poolT_kernel(
    const bf16* __restrict__ yin, const float* __restrict__ stat, bf16* __restrict__ outp)
{
  __shared__ bf16 buf[C][TH + 2];
  const int n = blockIdx.x, tid = threadIdx.x;
  const uint* src = (const uint*)(yin + (size_t)n*C*TH*2);
  for (int i = tid; i < C*TH; i += 256) {
    int th = i & (TH - 1), c = i / TH;
    uint u = src[i];
    float sc = stat[256 + c], sh = stat[384 + c];
    float a = fmaxf(sc*bflo(u) + sh, 0.f);
    float b = fmaxf(sc*bfhi(u) + sh, 0.f);
    buf[c][th] = (bf16)fmaxf(a, b);
  }
  __syncthreads();
  bf16* dst = outp + (size_t)n*TH*C;
  for (int i = tid; i < TH*C/2; i += 256) {
    int cp = i & (C/2 - 1), th = i / (C/2);
    union { bf16 h[2]; uint u; } pk;
    pk.h[0] = buf[2*cp][th]; pk.h[1] = buf[2*cp + 1][th];
    *(uint*)&dst[th*C + 2*cp] = pk.u;
  }
}

// ---------------- fused biLSTM (proven R5 config): 16 nodes/block, 8 waves ----------------
__global__ __launch_bounds__(512, 2) void lstm_fused_kernel(
    const bf16* __restrict__ p2t, const bf16* __restrict__ wih_g,
    const bf16* __restrict__ whh_g, const float* __restrict__ bias_g,
    float* __restrict__ hsum)
{
  __shared__ bf16 hb[2][2048];   // [buf][16 n][128 hh], 256B rows, swizzled
  const int z = blockIdx.x;
  const int dir = z & 1, n0 = (z >> 1)*16;
  const int tid = threadIdx.x, lane = tid & 63, wv = tid >> 6;
  const int l15 = lane & 15, lh = lane >> 4;
  i32x4 wihr[4][4], whhr[4][4];
  {
    const bf16* wi = wih_g + (size_t)dir*65536;
    const bf16* wh = whh_g + (size_t)dir*65536;
    #pragma unroll
    for (int cf = 0; cf < 4; ++cf) {
      int c = wv*64 + cf*16 + l15;
      #pragma unroll
      for (int ks = 0; ks < 4; ++ks) {
        wihr[cf][ks] = *(const i32x4*)(wi + (size_t)c*128 + ks*32 + lh*8);
        whhr[cf][ks] = *(const i32x4*)(wh + (size_t)c*128 + ks*32 + lh*8);
      }
    }
  }
  f32x4 bias4[4];
  #pragma unroll
  for (int cf = 0; cf < 4; ++cf) {
    int hh = wv*16 + cf*4 + lh;
    bias4[cf] = *(const f32x4*)&bias_g[dir*512 + hh*4];
  }
  for (int i = tid; i < 256; i += 512) ((i32x4*)hb[0])[i] = (i32x4){0,0,0,0};
  const bf16* xrow = p2t + (size_t)(n0 + l15)*128*128;
  float creg[4] = {0.f,0.f,0.f,0.f}, hac[4] = {0.f,0.f,0.f,0.f};
  f32x4 acc[4];
  i32x4 xn[4];
  {
    int ts0 = dir ? 127 : 0;
    #pragma unroll
    for (int ks = 0; ks < 4; ++ks)
      xn[ks] = *(const i32x4*)(xrow + (size_t)ts0*128 + ks*32 + lh*8);
    #pragma unroll
    for (int cf = 0; cf < 4; ++cf) {
      acc[cf] = mfma16(wihr[cf][0], xn[0], bias4[cf]);
      #pragma unroll
      for (int ks = 1; ks < 4; ++ks)
        acc[cf] = mfma16(wihr[cf][ks], xn[ks], acc[cf]);
    }
  }
  int cur = 0;
  __syncthreads();
  for (int t = 0; t < 128; ++t) {
    {
      int tn = (t + 1 < 128) ? t + 1 : 127;
      int tsn = dir ? 127 - tn : tn;
      #pragma unroll
      for (int ks = 0; ks < 4; ++ks)
        xn[ks] = *(const i32x4*)(xrow + (size_t)tsn*128 + ks*32 + lh*8);
    }
    {
      i32x4 a0 = *(const i32x4*)swz256((char*)hb[cur], l15, 0*64 + lh*16);
      i32x4 a1 = *(const i32x4*)swz256((char*)hb[cur], l15, 1*64 + lh*16);
      #pragma unroll
      for (int cf = 0; cf < 4; ++cf) {
        acc[cf] = mfma16(whhr[cf][0], a0, acc[cf]);
        acc[cf] = mfma16(whhr[cf][1], a1, acc[cf]);
      }
      a0 = *(const i32x4*)swz256((char*)hb[cur], l15, 2*64 + lh*16);
      a1 = *(const i32x4*)swz256((char*)hb[cur], l15, 3*64 + lh*16);
      #pragma unroll
      for (int cf = 0; cf < 4; ++cf) {
        acc[cf] = mfma16(whhr[cf][2], a0, acc[cf]);
        acc[cf] = mfma16(whhr[cf][3], a1, acc[cf]);
      }
    }
    #pragma unroll
    for (int cf = 0; cf < 4; ++cf) {
      float ig = sigf_(acc[cf][0]);
      float fg = sigf_(acc[cf][1]);
      float gg = tanhx_(acc[cf][2]);
      float og = sigf_(acc[cf][3]);
      float cv = fg*creg[cf] + ig*gg;
      creg[cf] = cv;
      float hv = og*tanhx_(cv);
      hac[cf] += hv;
      int hh = wv*16 + cf*4 + lh;
      *(bf16*)swz256((char*)hb[cur^1], l15, hh*2) = (bf16)hv;
    }
    #pragma unroll
    for (int cf = 0; cf < 4; ++cf) {
      acc[cf] = mfma16(wihr[cf][0], xn[0], bias4[cf]);
      #pragma unroll
      for (int ks = 1; ks < 4; ++ks)
        acc[cf] = mfma16(wihr[cf][ks], xn[ks], acc[cf]);
    }
    __syncthreads();
    cur ^= 1;
  }
  float* hm = hsum + ((size_t)dir*2048 + n0)*128;
  #pragma unroll
  for (int cf = 0; cf < 4; ++cf) {
    int hh = wv*16 + cf*4 + lh;
    hm[(size_t)l15*128 + hh] = hac[cf];
  }
}

// ---------------- feats = mean over T of [hf, hr] ----------------
__global__ __launch_bounds__(256) void feats_kernel(const float* __restrict__ hsum, float* __restrict__ feats)
{
  int idx = blockIdx.x*256 + threadIdx.x;
  int k = idx & 255, n = idx >> 8;
  float v = (k < 128) ? hsum[(size_t)n*128 + k]
                      : hsum[(size_t)2048*128 + (size_t)n*128 + (k - 128)];
  feats[idx] = v * 0.0078125f;
}

// ---------------- Wh = in @ W^T; also emits WhT bf16 [128][2048] ----------------
template<int K>
__global__ __launch_bounds__(256) void node_gemm_kernel(
    const float* __restrict__ inp, const float* __restrict__ W,
    float* __restrict__ outp, bf16* __restrict__ outT)
{
  __shared__ float ft[32][K];
  const int i0 = blockIdx.x*32, tid = threadIdx.x;
  for (int i = tid; i < 32*K; i += 256) ft[i/K][i%K] = inp[(size_t)i0*K + i];
  __syncthreads();
  const int f = tid & 127, ih = (tid >> 7)*16;
  float acc[16];
  #pragma unroll
  for (int ii = 0; ii < 16; ++ii) acc[ii] = 0.f;
  const float* wp = W + (size_t)f*K;
  for (int k = 0; k < K; k += 4) {
    const float4 wv = *reinterpret_cast<const float4*>(&wp[k]);
    #pragma unroll
    for (int ii = 0; ii < 16; ++ii) {
      const float* fp = &ft[ih+ii][k];
      acc[ii] += fp[0]*wv.x + fp[1]*wv.y + fp[2]*wv.z + fp[3]*wv.w;
    }
  }
  union { bf16 h[16]; uint4 u[2]; } pk;
  #pragma unroll
  for (int ii = 0; ii < 16; ++ii) {
    outp[(size_t)(i0+ih+ii)*128 + f] = acc[ii];
    pk.h[ii] = (bf16)acc[ii];
  }
  uint4* dT = (uint4*)&outT[(size_t)f*2048 + i0 + ih];
  dT[0] = pk.u[0]; dT[1] = pk.u[1];
}

// ---------------- s1/s2 per node ----------------
__global__ __launch_bounds__(256) void gat_s_kernel(const float* __restrict__ Wh,
    const float* __restrict__ a, float* __restrict__ s1, float* __restrict__ s2)
{
  const int node = blockIdx.x*4 + (threadIdx.x >> 6);
  const int l = threadIdx.x & 63;
  const float w0 = Wh[(size_t)node*128 + l], w1 = Wh[(size_t)node*128 + 64 + l];
  float v1 = w0*a[l]     + w1*a[64+l];
  float v2 = w0*a[128+l] + w1*a[192+l];
  #pragma unroll
  for (int off = 32; off > 0; off >>= 1) { v1 += __shfl_down(v1, off); v2 += __shfl_down(v2, off); }
  if (l == 0) { s1[node] = v1; s2[node] = v2; }
}

// ---------------- GAT attention, 8 rows/block (grid 256, 2 blocks/CU) ----------------
// Phase 1: wave w computes softmax row w into P (bf16, 32KB swizzled LDS).
// Phase 2: wave w computes out[8 rows][f-tile w*16..+16) = P @ WhT via 64 MFMA (M half-wasted).
__global__ __launch_bounds__(512) void gat_attn8_kernel(
    const bf16* __restrict__ WhT,
    const float* __restrict__ s1, const float* __restrict__ s2v,
    const int* __restrict__ adj, float* __restrict__ outp, int applyElu)
{
  __shared__ bf16 P[8*2048];     // rows of 4096B, swizzled
  __shared__ float sums[8];
  const int i0 = blockIdx.x*8, tid = threadIdx.x;
  const int lane = tid & 63, w = tid >> 6;
  {
    const int r = w, i = i0 + r;
    const float s1i = s1[i];
    const int4* arow = (const int4*)(adj + (size_t)i*2048);
    float ev[8][4];
    float m = -3.0e38f;
    #pragma unroll
    for (int k = 0; k < 8; ++k) {
      int4 ad = arow[k*64 + lane];
      float4 sv = *(const float4*)&s2v[k*256 + lane*4];
      float e0 = s1i + sv.x; e0 = (e0 > 0.f) ? e0 : 0.2f*e0; e0 = (ad.x > 0) ? e0 : -3.0e38f;
      float e1 = s1i + sv.y; e1 = (e1 > 0.f) ? e1 : 0.2f*e1; e1 = (ad.y > 0) ? e1 : -3.0e38f;
      float e2 = s1i + sv.z; e2 = (e2 > 0.f) ? e2 : 0.2f*e2; e2 = (ad.z > 0) ? e2 : -3.0e38f;
      float e3 = s1i + sv.w; e3 = (e3 > 0.f) ? e3 : 0.2f*e3; e3 = (ad.w > 0) ? e3 : -3.0e38f;
      ev[k][0]=e0; ev[k][1]=e1; ev[k][2]=e2; ev[k][3]=e3;
      m = fmaxf(m, fmaxf(fmaxf(e0,e1), fmaxf(e2,e3)));
    }
    #pragma unroll
    for (int off = 32; off > 0; off >>= 1) m = fmaxf(m, __shfl_xor(m, off));
    float s = 0.f;
    char* prow = (char*)P + r*4096;
    #pragma unroll
    for (int k = 0; k < 8; ++k) {
      float p0 = __expf(ev[k][0] - m);
      float p1 = __expf(ev[k][1] - m);
      float p2 = __expf(ev[k][2] - m);
      float p3 = __expf(ev[k][3] - m);
      s += (p0+p1)+(p2+p3);
      union { bf16 h[4]; uint2 u; } pk;
      pk.h[0]=(bf16)p0; pk.h[1]=(bf16)p1; pk.h[2]=(bf16)p2; pk.h[3]=(bf16)p3;
      *(uint2*)(prow + ((k*512 + lane*8) ^ ((r&7)<<4))) = pk.u;
    }
    #pragma unroll
    for (int off = 32; off > 0; off >>= 1) s += __shfl_xor(s, off);
    if (lane == 0) sums[r] = s;
  }
  __syncthreads();
  const int l15 = lane & 15, lh = lane >> 4;
  const int pr = l15 & 7;            // P row (rows 8-15 duplicate 0-7; outputs discarded)
  const bf16* bT = WhT + (size_t)(w*16 + l15)*2048;
  f32x4 ac[4];
  #pragma unroll
  for (int q = 0; q < 4; ++q) ac[q] = (f32x4){0.f,0.f,0.f,0.f};
  for (int kt = 0; kt < 64; kt += 4) {
    #pragma unroll
    for (int q = 0; q < 4; ++q) {
      i32x4 af = *(const i32x4*)((char*)P + pr*4096 + (((kt+q)*64 + lh*16) ^ ((pr&7)<<4)));
      i32x4 bf = *(const i32x4*)(bT + (kt+q)*32 + lh*8);
      ac[q] = mfma16(af, bf, ac[q]);
    }
  }
  f32x4 accv = (ac[0] + ac[1]) + (ac[2] + ac[3]);
  if (lh < 2) {
    #pragma unroll
    for (int rg = 0; rg < 4; ++rg) {
      int row = lh*4 + rg;           // 0..7
      float v = accv[rg] / sums[row];
      if (applyElu) v = (v > 0.f) ? v : (__expf(v) - 1.0f);
      outp[(size_t)(i0 + row)*128 + w*16 + l15] = v;
    }
  }
}

// ---------------- launch ----------------
extern "C" void kernel_launch(void* const* d_in, const int* in_sizes, int n_in,
                              void* d_out, int out_size, void* d_ws, size_t ws_size,
                              hipStream_t stream)
{
  (void)in_sizes; (void)n_in; (void)out_size; (void)ws_size;
  const float* x    = (const float*)d_in[0];
  const int*   adj  = (const int*)d_in[1];
  const float* c1w  = (const float*)d_in[2];
  const float* c1b  = (const float*)d_in[3];
  const float* bn1g = (const float*)d_in[4];
  const float* bn1b = (const float*)d_in[5];
  const float* c2w  = (const float*)d_in[6];
  const float* c2b  = (const float*)d_in[7];
  const float* bn2g = (const float*)d_in[8];
  const float* bn2b = (const float*)d_in[9];
  const float* wif  = (const float*)d_in[10];
  const float* whf  = (const float*)d_in[11];
  const float* bfv  = (const float*)d_in[12];
  const float* wir  = (const float*)d_in[13];
  const float* whr  = (const float*)d_in[14];
  const float* brv  = (const float*)d_in[15];
  const float* g1W  = (const float*)d_in[16];
  const float* g1a  = (const float*)d_in[17];
  const float* g2W  = (const float*)d_in[18];
  const float* g2a  = (const float*)d_in[19];
  float* outp = (float*)d_out;
  float* ws   = (float*)d_ws;

  bf16* y12    = (bf16*)(ws + OFF_A);
  bf16* pool1t = (bf16*)(ws + OFF_B);      // [2048][256][64]
  bf16* pool2t = (bf16*)(ws + OFF_B1);     // [2048][128][128]
  bf16* whh_g  = (bf16*)(ws + OFF_WHHG);
  bf16* wih_g  = (bf16*)(ws + OFF_WIHG);
  float* bias_g= ws + OFF_BIAS;
  float* hsm   = ws + OFF_HSUM;
  float* feats = ws + OFF_FEAT;
  float* Wh1   = ws + OFF_WH1;
  float* s1a   = ws + OFF_S1A;
  float* s2a   = ws + OFF_S2A;
  float* h1    = ws + OFF_H1;
  float* Wh2   = ws + OFF_WH2;
  float* s1b   = ws + OFF_S1B;
  float* s2b   = ws + OFF_S2B;
  float* stat  = ws + OFF_STAT;
  bf16* w1p    = (bf16*)(ws + OFF_W1P);
  bf16* w2p    = (bf16*)(ws + OFF_W2P);
  bf16* whT    = (bf16*)(ws + OFF_WHT);
  float* statp = ws + OFF_STATP;

  prep_kernel<<<dim3(256,2),256,0,stream>>>(whf, whr, wif, wir, bfv, brv, c1w, c2w,
                                            whh_g, wih_g, bias_g, w1p, w2p);

  // conv1 (+BN stats) -> finalize -> pool (+transpose)
  hipMemsetAsync(statp, 0, 8192*sizeof(float), stream);
  conv1_kernel<<<256,512,0,stream>>>(x, w1p, c1b, y12, statp);
  bn_finalize_kernel<<<1,128,0,stream>>>(statp, stat, bn1g, bn1b, 64, 1.0f/(2048.0f*512.0f));
  poolT_kernel<64,256><<<2048,256,0,stream>>>(y12, stat, pool1t);

  // conv2 (+BN stats) -> finalize -> pool (+transpose)
  hipMemsetAsync(statp, 0, 8192*sizeof(float), stream);
  conv2_kernel<<<256,512,0,stream>>>(pool1t, w2p, c2b, y12, statp);
  bn_finalize_kernel<<<1,128,0,stream>>>(statp, stat, bn2g, bn2b, 128, 1.0f/(2048.0f*256.0f));
  poolT_kernel<128,128><<<2048,256,0,stream>>>(y12, stat, pool2t);

  // fused biLSTM (single dispatch, proven R5 config)
  lstm_fused_kernel<<<256,512,0,stream>>>(pool2t, wih_g, whh_g, bias_g, hsm);
  feats_kernel<<<2048,256,0,stream>>>(hsm, feats);

  // GAT x2
  node_gemm_kernel<256><<<64,256,0,stream>>>(feats, g1W, Wh1, whT);
  gat_s_kernel<<<512,256,0,stream>>>(Wh1, g1a, s1a, s2a);
  gat_attn8_kernel<<<256,512,0,stream>>>(whT, s1a, s2a, adj, h1, 1);
  node_gemm_kernel<128><<<64,256,0,stream>>>(h1, g2W, Wh2, whT);
  gat_s_kernel<<<512,256,0,stream>>>(Wh2, g2a, s1b, s2b);
  gat_attn8_kernel<<<256,512,0,stream>>>(whT, s1b, s2b, adj, outp, 0);
}